// Round 17
// baseline (164.601 us; speedup 1.0000x reference)
//
#include <hip/hip_runtime.h>
#include <hip/hip_bf16.h>
#include <math.h>

typedef unsigned int uint;
typedef unsigned long long u64;

#define BB 4
#define NN 100000
#define PRE 6000
#define POST 1000
#define NWRD 94          // 6000/64 rounded up
#define PREF 2048        // NMS prefix (exact if >=1000 kept inside; else fallback)
#define PWRD 32          // PREF/64
#define SCAP 8192        // bucketed capacity
#define ROWP 6016        // padded rows/cols
#define KSUP 64          // max suppressors tracked per box
#define NRANGE 32        // hist ranges per image (2048 bins each)
#define WQ 16            // col-words per sup_build block

// ---- workspace layout (bytes) ----
constexpr size_t OFF_HDR   = 0;                                    // uints: t1[4], limit[4], done[4]
constexpr size_t OFF_RTOT  = 64;                                   // 128 uints: per-(b,range) totals
constexpr size_t OFF_CNT   = 1024;                                 // BB*ROWP*4 (zeroed by hist_range)
constexpr size_t OFF_H1    = OFF_CNT + (size_t)BB*ROWP*4;          // hist1: 1MB (fully overwritten)
constexpr size_t OFF_BASE  = OFF_H1  + (size_t)BB*65536*4;         // base:  1MB (fully overwritten)
constexpr size_t OFF_KEY   = OFF_BASE+ (size_t)BB*65536*4;         // keyhi: BB*NN*4
constexpr size_t OFF_BUCK  = OFF_KEY + (size_t)BB*NN*4;            // keys:  BB*SCAP*8
constexpr size_t OFF_BBOX  = OFF_BUCK+ (size_t)BB*SCAP*8;          // boxes: BB*SCAP*16
constexpr size_t OFF_BSC   = OFF_BBOX+ (size_t)BB*SCAP*16;         // score: BB*SCAP*4
constexpr size_t OFF_LIST  = OFF_BSC + (size_t)BB*SCAP*4;          // BB*ROWP*KSUP*4
constexpr size_t OFF_BOX   = OFF_LIST+ (size_t)BB*ROWP*KSUP*4;
constexpr size_t OFF_SCO   = OFF_BOX + (size_t)BB*ROWP*16;
constexpr size_t OFF_AREA  = OFF_SCO + (size_t)BB*ROWP*4;
constexpr size_t OFF_VAL   = OFF_AREA+ (size_t)BB*ROWP*4;          // validW (zeroed by scan128)

__device__ __forceinline__ float clipf(float v, float hi) {
  return fminf(fmaxf(v, 0.0f), hi);
}

// ---------- pass 1a: keys only (pure streaming, no atomics) ----------
__global__ void keys_only(const float4* __restrict__ props,
                          const float2* __restrict__ clsp,
                          uint* __restrict__ keyhi) {
  int b = blockIdx.y;
  int i = blockIdx.x * 256 + threadIdx.x;
  if (i >= NN) return;
  float4 p = props[(size_t)b * NN + i];
  float x1 = clipf(p.x, 800.0f), y1 = clipf(p.y, 800.0f);
  float x2 = clipf(p.z, 800.0f), y2 = clipf(p.w, 800.0f);
  bool valid = ((x2 - x1) >= 16.0f) && ((y2 - y1) >= 16.0f);
  float s  = clsp[(size_t)b * NN + i].y;
  float sm = valid ? s : -INFINITY;
  uint u = __float_as_uint(sm);
  u = (u & 0x80000000u) ? ~u : (u | 0x80000000u);  // monotonic: ascending u == ascending score
  keyhi[(size_t)b * NN + i] = ~u;                   // ascending key == DESCENDING score
}

// ---------- pass 1b: range-partitioned LDS histogram -> hist1 + rtot ----------
__global__ __launch_bounds__(256) void hist_range(const uint4* __restrict__ keyhi4,
                                                  uint* __restrict__ hist1,
                                                  uint* __restrict__ rtot,
                                                  uint* __restrict__ cnt) {
  int b = blockIdx.y;
  int r = blockIdx.x;
  uint lo = (uint)r << 11;     // 2048 bins per range block
  __shared__ uint lh[2048];
  __shared__ uint wr[4];
  int tid = threadIdx.x, lane = tid & 63, W = tid >> 6;
  for (int i = tid; i < 2048; i += 256) lh[i] = 0u;
  __syncthreads();
  const uint4* K = keyhi4 + (size_t)b * (NN / 4);
  for (int i = tid; i < NN / 4; i += 256) {
    uint4 v = K[i];
    uint b0 = (v.x >> 16) - lo; if (b0 < 2048u) atomicAdd(&lh[b0], 1u);
    uint b1 = (v.y >> 16) - lo; if (b1 < 2048u) atomicAdd(&lh[b1], 1u);
    uint b2 = (v.z >> 16) - lo; if (b2 < 2048u) atomicAdd(&lh[b2], 1u);
    uint b3 = (v.w >> 16) - lo; if (b3 < 2048u) atomicAdd(&lh[b3], 1u);
  }
  __syncthreads();
  uint* H = hist1 + (size_t)b * 65536 + lo;
  uint s = 0;
  for (int i = tid; i < 2048; i += 256) { H[i] = lh[i]; s += lh[i]; }
  for (int off = 32; off > 0; off >>= 1) s += __shfl_xor(s, off);
  if (lane == 0) wr[W] = s;
  __syncthreads();
  if (tid == 0) rtot[b * 32 + r] = wr[0] + wr[1] + wr[2] + wr[3];
  uint* C = cnt + (size_t)b * ROWP + r * (ROWP / NRANGE);
  if (tid < ROWP / NRANGE) C[tid] = 0u;
}

// ---------- pass 2: per-range exclusive scan -> base[]; boundary -> hdr ----------
__global__ __launch_bounds__(256) void scan128(const uint* __restrict__ hist1,
                                               const uint* __restrict__ rtot,
                                               uint* __restrict__ base,
                                               uint* __restrict__ hdr,
                                               u64* __restrict__ validW) {
  int r = blockIdx.x, b = blockIdx.y;
  int tid = threadIdx.x, lane = tid & 63, W = tid >> 6;
  __shared__ uint wt[4];
  if (r == 0 && tid < 96) validW[(size_t)b * 96 + tid] = 0ull;
  uint lo = (uint)r << 11;
  uint rbase = 0, tot = 0;
  for (int k = 0; k < 32; ++k) {
    uint v = rtot[b * 32 + k];
    if (k < r) rbase += v;
    if (k == r) tot = v;
  }
  const uint* h = hist1 + (size_t)b * 65536 + lo;
  uint c[8], s = 0;
  for (int k = 0; k < 8; ++k) { c[k] = h[tid * 8 + k]; s += c[k]; }
  uint ps = s;
  for (int off = 1; off < 64; off <<= 1) {
    uint v = __shfl_up(ps, off);
    if (lane >= off) ps += v;
  }
  if (lane == 63) wt[W] = ps;
  __syncthreads();
  uint wbase = 0;
  for (int k = 0; k < 4; ++k) { if (k < W) wbase += wt[k]; }
  uint excl = rbase + wbase + ps - s;     // global exclusive before thread's bins
  uint run = excl;
  uint* bs = base + (size_t)b * 65536 + lo;
  for (int k = 0; k < 8; ++k) { bs[tid * 8 + k] = run; run += c[k]; }
  if (rbase < (uint)PRE && (uint)PRE <= rbase + tot) {
    uint cc = excl;
    for (int k = 0; k < 8; ++k) {
      uint hv = c[k];
      if (cc < (uint)PRE && (uint)PRE <= cc + hv) {
        hdr[0 + b] = lo + (uint)(tid * 8 + k);   // t1 boundary bucket
        hdr[4 + b] = cc + hv;                    // limit = cumulative through t1
      }
      cc += hv;
    }
  }
}

// ---------- pass 3: scatter full records of selected elems into bucket slots ----
// High-TLP phase (400K threads) absorbs the random props/clsp gather latency.
__global__ void bucket_scatter(const uint* __restrict__ keyhi,
                               uint* __restrict__ base,
                               const uint* __restrict__ hdr,
                               const float4* __restrict__ props,
                               const float2* __restrict__ clsp,
                               u64* __restrict__ buck,
                               float4* __restrict__ buckBox,
                               float* __restrict__ buckSc) {
  int b = blockIdx.y;
  int i = blockIdx.x * 256 + threadIdx.x;
  if (i >= NN) return;
  uint kh = keyhi[(size_t)b * NN + i];
  if ((kh >> 16) <= hdr[0 + b]) {
    uint pos = atomicAdd(&base[(size_t)b * 65536 + (kh >> 16)], 1u);
    if (pos < SCAP) {
      buck[(size_t)b * SCAP + pos] = ((u64)kh << 32) | (uint)i;
      float4 p = props[(size_t)b * NN + i];
      float4 bx;
      bx.x = clipf(p.x, 800.0f); bx.y = clipf(p.y, 800.0f);
      bx.z = clipf(p.z, 800.0f); bx.w = clipf(p.w, 800.0f);
      buckBox[(size_t)b * SCAP + pos] = bx;
      buckSc [(size_t)b * SCAP + pos] = clsp[(size_t)b * NN + i].y;
    }
  }
}

// ---------- pass 4: exact rank -> copy record from slot to rank row ----------
// All reads are L2-hot slot arrays; no random gathers.
__global__ void rank_scatter(const u64* __restrict__ buck,
                             const float4* __restrict__ buckBox,
                             const float* __restrict__ buckSc,
                             const uint* __restrict__ base,
                             const uint* __restrict__ hist,
                             const uint* __restrict__ hdr,
                             float4* __restrict__ boxes6k,
                             float* __restrict__ score6k,
                             float* __restrict__ area6k,
                             u64* __restrict__ validW) {
  int b = blockIdx.y;
  int s = blockIdx.x * 256 + threadIdx.x;
  uint limit = hdr[4 + b];
  if (s >= (int)limit) return;
  u64 v = buck[(size_t)b * SCAP + s];
  float4 bx = buckBox[(size_t)b * SCAP + s];
  float sc = buckSc[(size_t)b * SCAP + s];
  uint bkt = (uint)(v >> 48);
  uint cntb = hist[(size_t)b * 65536 + bkt];
  uint b0 = base[(size_t)b * 65536 + bkt] - cntb;  // restore pre-scatter base
  uint r = b0;
  for (uint m = 0; m < cntb; ++m) {
    u64 w = buck[(size_t)b * SCAP + b0 + m];
    r += (w < v) ? 1u : 0u;                        // (key,idx) stable order
  }
  if (r >= (uint)PRE) return;
  float w = bx.z - bx.x, h = bx.w - bx.y;
  bool valid = (w >= 16.0f) && (h >= 16.0f);
  boxes6k[(size_t)b * ROWP + r] = bx;
  score6k[(size_t)b * ROWP + r] = sc;
  area6k [(size_t)b * ROWP + r] = fmaxf(w, 0.0f) * fmaxf(h, 0.0f);
  if (valid) atomicOr(&validW[(size_t)b * 96 + (r >> 6)], 1ull << (r & 63));
}

// ---------- shared sup tile body (exact division-free IoU test) ----------
// fl32(inter/un) > 0.7f  <=>  (double)inter >= M*(double)un,
// M = 0.7f + 2^-25 = 0x1.6666668p-1 (rounding midpoint; the tie
// rounds-to-even UP; 25b x 24b = 49 bits <= 53, conversions exact, un>0).
__device__ __forceinline__
void sup_tile(int b, int gb, int cw0, int wmax,
              const float4* boxes6k, const float* area6k, const u64* validW,
              uint* cnt, uint* list,
              float4* rbox, float* rar /* LDS, filled here */) {
  int w = threadIdx.x >> 6, lane = threadIdx.x & 63;
  if (threadIdx.x < 64) {
    rbox[lane] = boxes6k[(size_t)b * ROWP + gb * 64 + lane];
    rar[lane]  = area6k [(size_t)b * ROWP + gb * 64 + lane];
  }
  __syncthreads();
  u64 vmask = validW[(size_t)b * 96 + gb];

  int    cw[4];
  u64    rowsel[4], bits[4];
  float4 cbox[4];
  float  carea[4];
  #pragma unroll
  for (int k = 0; k < 4; ++k) {
    cw[k] = cw0 + 4 * k + w;            // wave w owns words cw0+w, +4, +8, +12
    int col = cw[k] * 64 + lane;
    int colc = col < (ROWP - 1) ? col : (ROWP - 1);
    cbox[k]  = boxes6k[(size_t)b * ROWP + colc];
    carea[k] = area6k [(size_t)b * ROWP + colc];
    rowsel[k] = (cw[k] > gb) ? vmask
              : ((cw[k] == gb && lane) ? (vmask & ((1ull << lane) - 1ull)) : 0ull);
    bits[k] = 0ull;
  }

  const double M = 0x1.6666668p-1;      // exact decision midpoint for (iou > 0.7f)
  #pragma unroll 4
  for (int r = 0; r < 64; ++r) {
    float4 rb = rbox[r];
    float  ra = rar[r];
    u64 m = 1ull << r;
    #pragma unroll
    for (int k = 0; k < 4; ++k) {
      float xx1 = fmaxf(rb.x, cbox[k].x), yy1 = fmaxf(rb.y, cbox[k].y);
      float xx2 = fminf(rb.z, cbox[k].z), yy2 = fminf(rb.w, cbox[k].w);
      float inter = fmaxf(xx2 - xx1, 0.0f) * fmaxf(yy2 - yy1, 0.0f);
      float un = fmaxf(ra + carea[k] - inter, 1e-9f);
      bits[k] |= ((double)inter >= M * (double)un) ? m : 0ull;
    }
  }

  int rbase = gb * 64;
  #pragma unroll
  for (int k = 0; k < 4; ++k) {
    if (cw[k] >= wmax) continue;
    u64 bt = bits[k] & rowsel[k];
    int col = cw[k] * 64 + lane;
    while (bt) {
      int r = __ffsll((long long)bt) - 1;
      bt &= bt - 1;
      uint pos = atomicAdd(&cnt[(size_t)b * ROWP + col], 1u);
      if (pos < KSUP) list[((size_t)b * ROWP + col) * KSUP + pos] = (uint)(rbase + r);
    }
  }
}

// ---------- pass 5a: suppressor lists within prefix [0, PREF) ----------
__global__ __launch_bounds__(256) void sup_build_pre(const float4* __restrict__ boxes6k,
                                                     const float* __restrict__ area6k,
                                                     const u64* __restrict__ validW,
                                                     uint* __restrict__ cnt,
                                                     uint* __restrict__ list) {
  int gb = blockIdx.y, b = blockIdx.z;
  int cw0 = blockIdx.x * WQ;            // 0 or 16
  if (cw0 + WQ - 1 < gb) return;        // fully below diagonal
  __shared__ float4 rbox[64];
  __shared__ float  rar[64];
  sup_tile(b, gb, cw0, PWRD, boxes6k, area6k, validW, cnt, list, rbox, rar);
}

// ---------- pass 5b: fallback — remaining tiles, only if !done[b] ----------
__global__ __launch_bounds__(256) void sup_build_full(const float4* __restrict__ boxes6k,
                                                      const float* __restrict__ area6k,
                                                      const u64* __restrict__ validW,
                                                      const uint* __restrict__ hdr,
                                                      uint* __restrict__ cnt,
                                                      uint* __restrict__ list) {
  int gb = blockIdx.y, b = blockIdx.z;
  if (hdr[8 + b]) return;               // prefix sufficed for this image
  int cw0 = blockIdx.x * WQ;
  if (cw0 + WQ - 1 < gb) return;        // fully below diagonal
  if (gb < PWRD && cw0 + WQ <= PWRD) return;  // prefix tiles already built
  __shared__ float4 rbox[64];
  __shared__ float  rar[64];
  sup_tile(b, gb, cw0, NWRD, boxes6k, area6k, validW, cnt, list, rbox, rar);
}

// ---------- pass 6a: prefix resolve + finalize; sets done[b] ----------
__global__ __launch_bounds__(1024) void resolve_pre(const uint* __restrict__ cnt,
                                                    const uint* __restrict__ list,
                                                    const u64* __restrict__ validW,
                                                    const float* __restrict__ score6k,
                                                    const float4* __restrict__ boxes6k,
                                                    uint* __restrict__ hdr,
                                                    float* __restrict__ out) {
  int b = blockIdx.x, tid = threadIdx.x;
  __shared__ u64 ALIVE[PWRD], DEC[PWRD], VW[PWRD];
  __shared__ int changed;
  if (tid < PWRD) {
    ALIVE[tid] = 0ull; DEC[tid] = 0ull;
    VW[tid] = validW[(size_t)b * 96 + tid];
  }
  __syncthreads();

  uint myCnt[2];
  #pragma unroll
  for (int r = 0; r < 2; ++r) {
    int j = tid + r * 1024;
    myCnt[r] = (j < PREF) ? cnt[(size_t)b * ROWP + j] : 0u;
  }
  #pragma unroll
  for (int r = 0; r < 2; ++r) {
    int j = tid + r * 1024;
    if (j >= PREF) continue;
    bool valid = (VW[j >> 6] >> (j & 63)) & 1ull;
    if (myCnt[r] == 0u || !valid) {
      atomicOr(&DEC[j >> 6], 1ull << (j & 63));
      if (valid) atomicOr(&ALIVE[j >> 6], 1ull << (j & 63));
    }
  }
  __syncthreads();

  while (true) {
    if (tid == 0) changed = 0;
    __syncthreads();
    int decJ[2]; bool decAlive[2];
    #pragma unroll
    for (int r = 0; r < 2; ++r) {
      decJ[r] = -1; decAlive[r] = false;
      int j = tid + r * 1024;
      if (j >= PREF || myCnt[r] == 0u) continue;
      if ((DEC[j >> 6] >> (j & 63)) & 1ull) continue;
      const uint* lj = list + ((size_t)b * ROWP + j) * KSUP;
      uint c = myCnt[r] < KSUP ? myCnt[r] : KSUP;
      bool anyAlive = false, pending = false;
      for (uint m = 0; m < c; ++m) {
        uint i = lj[m];
        bool ai = (ALIVE[i >> 6] >> (i & 63)) & 1ull;
        bool di = (DEC[i >> 6] >> (i & 63)) & 1ull;
        if (ai) { anyAlive = true; break; }
        if (!di) pending = true;
      }
      if (anyAlive)      { decJ[r] = j; decAlive[r] = false; }
      else if (!pending) { decJ[r] = j; decAlive[r] = true;  }
    }
    __syncthreads();
    bool any = false;
    #pragma unroll
    for (int r = 0; r < 2; ++r) {
      if (decJ[r] >= 0) {
        int j = decJ[r];
        if (decAlive[r]) atomicOr(&ALIVE[j >> 6], 1ull << (j & 63));
        atomicOr(&DEC[j >> 6], 1ull << (j & 63));
        any = true;
      }
    }
    if (any) atomicAdd(&changed, 1);
    __syncthreads();
    if (changed == 0) break;
  }

  __shared__ uint psum[PWRD + 1];
  if (tid == 0) {
    uint c = 0;
    for (int w = 0; w < PWRD; ++w) { psum[w] = c; c += (uint)__popcll(ALIVE[w]); }
    psum[PWRD] = c;
    hdr[8 + b] = (c >= (uint)POST) ? 1u : 0u;
  }
  __syncthreads();
  if (psum[PWRD] < (uint)POST) return;   // fallback path will produce output

  for (int q = tid; q < POST; q += 1024) out[(size_t)b * POST + q] = 0.0f;
  for (int t = tid; t < POST * 4; t += 1024) out[(size_t)BB * POST + (size_t)b * POST * 4 + t] = 0.0f;
  __syncthreads();
  for (int j = tid; j < PREF; j += 1024) {
    int w = j >> 6, bit = j & 63;
    u64 word = ALIVE[w];
    if ((word >> bit) & 1ull) {
      uint rank = psum[w] + (uint)__popcll(word & ((1ull << bit) - 1ull));
      if (rank < POST) {
        out[(size_t)b * POST + rank] = score6k[(size_t)b * ROWP + j];
        float4 bx = boxes6k[(size_t)b * ROWP + j];
        float* o = out + (size_t)BB * POST + ((size_t)b * POST + rank) * 4;
        o[0] = bx.x; o[1] = bx.y; o[2] = bx.z; o[3] = bx.w;
      }
    }
  }
}

// ---------- pass 6b: full resolve + finalize (only if !done[b]) ----------
__global__ __launch_bounds__(1024) void resolve_full(const uint* __restrict__ cnt,
                                                     const uint* __restrict__ list,
                                                     const u64* __restrict__ validW,
                                                     const float* __restrict__ score6k,
                                                     const float4* __restrict__ boxes6k,
                                                     const uint* __restrict__ hdr,
                                                     float* __restrict__ out) {
  int b = blockIdx.x, tid = threadIdx.x;
  if (hdr[8 + b]) return;               // prefix path already produced output
  __shared__ u64 ALIVE[96], DEC[96], VW[96];
  __shared__ int changed;
  if (tid < 96) {
    ALIVE[tid] = 0ull; DEC[tid] = 0ull;
    VW[tid] = validW[(size_t)b * 96 + tid];
  }
  __syncthreads();

  uint myCnt[6];
  #pragma unroll
  for (int r = 0; r < 6; ++r) {
    int j = tid + r * 1024;
    myCnt[r] = (j < PRE) ? cnt[(size_t)b * ROWP + j] : 0u;
  }
  #pragma unroll
  for (int r = 0; r < 6; ++r) {
    int j = tid + r * 1024;
    if (j >= PRE) continue;
    bool valid = (VW[j >> 6] >> (j & 63)) & 1ull;
    if (myCnt[r] == 0u || !valid) {
      atomicOr(&DEC[j >> 6], 1ull << (j & 63));
      if (valid) atomicOr(&ALIVE[j >> 6], 1ull << (j & 63));
    }
  }
  __syncthreads();

  while (true) {
    if (tid == 0) changed = 0;
    __syncthreads();
    int decJ[6]; bool decAlive[6];
    #pragma unroll
    for (int r = 0; r < 6; ++r) {
      decJ[r] = -1; decAlive[r] = false;
      int j = tid + r * 1024;
      if (j >= PRE || myCnt[r] == 0u) continue;
      if ((DEC[j >> 6] >> (j & 63)) & 1ull) continue;
      const uint* lj = list + ((size_t)b * ROWP + j) * KSUP;
      uint c = myCnt[r] < KSUP ? myCnt[r] : KSUP;
      bool anyAlive = false, pending = false;
      for (uint m = 0; m < c; ++m) {
        uint i = lj[m];
        bool ai = (ALIVE[i >> 6] >> (i & 63)) & 1ull;
        bool di = (DEC[i >> 6] >> (i & 63)) & 1ull;
        if (ai) { anyAlive = true; break; }
        if (!di) pending = true;
      }
      if (anyAlive)      { decJ[r] = j; decAlive[r] = false; }
      else if (!pending) { decJ[r] = j; decAlive[r] = true;  }
    }
    __syncthreads();
    bool any = false;
    #pragma unroll
    for (int r = 0; r < 6; ++r) {
      if (decJ[r] >= 0) {
        int j = decJ[r];
        if (decAlive[r]) atomicOr(&ALIVE[j >> 6], 1ull << (j & 63));
        atomicOr(&DEC[j >> 6], 1ull << (j & 63));
        any = true;
      }
    }
    if (any) atomicAdd(&changed, 1);
    __syncthreads();
    if (changed == 0) break;
  }

  __shared__ uint psum[NWRD + 1];
  if (tid == 0) {
    uint c = 0;
    for (int w = 0; w < NWRD; ++w) { psum[w] = c; c += (uint)__popcll(ALIVE[w]); }
    psum[NWRD] = c;
  }
  __syncthreads();
  for (int q = tid; q < POST; q += 1024) out[(size_t)b * POST + q] = 0.0f;
  for (int t = tid; t < POST * 4; t += 1024) out[(size_t)BB * POST + (size_t)b * POST * 4 + t] = 0.0f;
  __syncthreads();
  for (int j = tid; j < PRE; j += 1024) {
    int w = j >> 6, bit = j & 63;
    u64 word = ALIVE[w];
    if ((word >> bit) & 1ull) {
      uint rank = psum[w] + (uint)__popcll(word & ((1ull << bit) - 1ull));
      if (rank < POST) {
        out[(size_t)b * POST + rank] = score6k[(size_t)b * ROWP + j];
        float4 bx = boxes6k[(size_t)b * ROWP + j];
        float* o = out + (size_t)BB * POST + ((size_t)b * POST + rank) * 4;
        o[0] = bx.x; o[1] = bx.y; o[2] = bx.z; o[3] = bx.w;
      }
    }
  }
}

extern "C" void kernel_launch(void* const* d_in, const int* in_sizes, int n_in,
                              void* d_out, int out_size, void* d_ws, size_t ws_size,
                              hipStream_t stream) {
  const float4* props = (const float4*)d_in[0];
  const float2* clsp  = (const float2*)d_in[1];
  float* out = (float*)d_out;
  char* ws = (char*)d_ws;

  uint*   hdr     = (uint*)(ws + OFF_HDR);
  uint*   rtot    = (uint*)(ws + OFF_RTOT);
  uint*   cnt     = (uint*)(ws + OFF_CNT);
  uint*   hist1   = (uint*)(ws + OFF_H1);
  uint*   base    = (uint*)(ws + OFF_BASE);
  uint*   keyhi   = (uint*)(ws + OFF_KEY);
  u64*    buck    = (u64*) (ws + OFF_BUCK);
  float4* buckBox = (float4*)(ws + OFF_BBOX);
  float*  buckSc  = (float*)(ws + OFF_BSC);
  uint*   list    = (uint*)(ws + OFF_LIST);
  float4* boxes6k = (float4*)(ws + OFF_BOX);
  float*  score6k = (float*)(ws + OFF_SCO);
  float*  area6k  = (float*)(ws + OFF_AREA);
  u64*    validW  = (u64*) (ws + OFF_VAL);

  dim3 gN((NN + 255) / 256, BB);
  keys_only<<<gN, 256, 0, stream>>>(props, clsp, keyhi);
  hist_range<<<dim3(NRANGE, BB), 256, 0, stream>>>((const uint4*)keyhi, hist1, rtot, cnt);
  scan128<<<dim3(NRANGE, BB), 256, 0, stream>>>(hist1, rtot, base, hdr, validW);
  bucket_scatter<<<gN, 256, 0, stream>>>(keyhi, base, hdr, props, clsp,
                                         buck, buckBox, buckSc);
  rank_scatter<<<dim3(SCAP / 256, BB), 256, 0, stream>>>(buck, buckBox, buckSc,
                                                         base, hist1, hdr,
                                                         boxes6k, score6k, area6k, validW);
  sup_build_pre<<<dim3(2, PWRD, BB), 256, 0, stream>>>(boxes6k, area6k, validW, cnt, list);
  resolve_pre<<<BB, 1024, 0, stream>>>(cnt, list, validW, score6k, boxes6k, hdr, out);
  sup_build_full<<<dim3((NWRD + WQ - 1) / WQ, NWRD, BB), 256, 0, stream>>>(boxes6k, area6k,
                                                                           validW, hdr, cnt, list);
  resolve_full<<<BB, 1024, 0, stream>>>(cnt, list, validW, score6k, boxes6k, hdr, out);
}

// Round 18
// 95.613 us; speedup vs baseline: 1.7215x; 1.7215x over previous
//
#include <hip/hip_runtime.h>
#include <hip/hip_bf16.h>
#include <math.h>

typedef unsigned int uint;
typedef unsigned short ushort;
typedef unsigned long long u64;

#define BB 4
#define NN 100000
#define PRE 6000
#define POST 1000
#define NWRD 94          // 6000/64 rounded up
#define PREF 2048        // NMS prefix (exact if >=1000 kept inside; else fallback)
#define PWRD 32          // PREF/64
#define SCAP 8192        // bucketed capacity
#define ROWP 6016        // padded rows/cols
#define KSUP 64          // max suppressors tracked per box
#define NRANGE 32        // hist ranges per image (2048 bins each)
#define WQ 16            // col-words per sup_build block

// ---- workspace layout (bytes) ----
constexpr size_t OFF_HDR   = 0;                                    // uints: t1[4], limit[4], done[4]
constexpr size_t OFF_RTOT  = 64;                                   // 128 uints: per-(b,range) totals
constexpr size_t OFF_CNT   = 1024;                                 // BB*ROWP*4 (zeroed by hist_range)
constexpr size_t OFF_H1    = OFF_CNT + (size_t)BB*ROWP*4;          // hist1: 1MB (fully overwritten)
constexpr size_t OFF_BASE  = OFF_H1  + (size_t)BB*65536*4;         // base:  1MB (fully overwritten)
constexpr size_t OFF_KEY   = OFF_BASE+ (size_t)BB*65536*4;         // keyhi: BB*NN*4
constexpr size_t OFF_BKT   = OFF_KEY + (size_t)BB*NN*4;            // bkts:  BB*NN*2 (ushort)
constexpr size_t OFF_BUCK  = OFF_BKT + (size_t)BB*NN*2;            // keys:  BB*SCAP*8
constexpr size_t OFF_BBOX  = OFF_BUCK+ (size_t)BB*SCAP*8;          // boxes: BB*SCAP*16
constexpr size_t OFF_BSC   = OFF_BBOX+ (size_t)BB*SCAP*16;         // score: BB*SCAP*4
constexpr size_t OFF_BBKT  = OFF_BSC + (size_t)BB*SCAP*4;          // bkt:   BB*SCAP*2
constexpr size_t OFF_LIST  = OFF_BBKT+ (size_t)BB*SCAP*2;          // BB*ROWP*KSUP*4
constexpr size_t OFF_BOX   = OFF_LIST+ (size_t)BB*ROWP*KSUP*4;
constexpr size_t OFF_SCO   = OFF_BOX + (size_t)BB*ROWP*16;
constexpr size_t OFF_AREA  = OFF_SCO + (size_t)BB*ROWP*4;
constexpr size_t OFF_VAL   = OFF_AREA+ (size_t)BB*ROWP*4;          // validW (zeroed by scan128)

__device__ __forceinline__ float clipf(float v, float hi) {
  return fminf(fmaxf(v, 0.0f), hi);
}

// Uniform, weakly key-monotone bucket map. Within-bucket ranking is by the
// exact (key,idx) compare, so ANY weakly monotone coarsening of the key is
// exact. Value-based binning makes bucket occupancy ~1.5 (vs ~390 for float
// bit-pattern binning, whose exponent clustering caused 390-iter mate loops).
__device__ __forceinline__ uint bucket_of(float s, bool valid) {
  if (!valid) return 65535u;
  float t = fminf(fmaxf(s, 0.0f), 1.0f);
  uint q = (uint)(t * 65536.0f);
  q = q > 65535u ? 65535u : q;
  return 65535u - q;                    // higher score -> lower bucket
}

// ---------- pass 1a: keys + buckets (pure streaming, no atomics) ----------
__global__ void keys_only(const float4* __restrict__ props,
                          const float2* __restrict__ clsp,
                          uint* __restrict__ keyhi,
                          ushort* __restrict__ bkts) {
  int b = blockIdx.y;
  int i = blockIdx.x * 256 + threadIdx.x;
  if (i >= NN) return;
  float4 p = props[(size_t)b * NN + i];
  float x1 = clipf(p.x, 800.0f), y1 = clipf(p.y, 800.0f);
  float x2 = clipf(p.z, 800.0f), y2 = clipf(p.w, 800.0f);
  bool valid = ((x2 - x1) >= 16.0f) && ((y2 - y1) >= 16.0f);
  float s  = clsp[(size_t)b * NN + i].y;
  float sm = valid ? s : -INFINITY;
  uint u = __float_as_uint(sm);
  u = (u & 0x80000000u) ? ~u : (u | 0x80000000u);  // monotonic: ascending u == ascending score
  keyhi[(size_t)b * NN + i] = ~u;                   // ascending key == DESCENDING score
  bkts[(size_t)b * NN + i] = (ushort)bucket_of(s, valid);
}

// ---------- pass 1b: range-partitioned LDS histogram over bkts ----------
// Invalid/last bucket (0xFFFF) counted in registers to avoid a same-address
// LDS atomic hotspot; added once per thread at the end.
__global__ __launch_bounds__(256) void hist_range(const uint4* __restrict__ bkts4,
                                                  uint* __restrict__ hist1,
                                                  uint* __restrict__ rtot,
                                                  uint* __restrict__ cnt) {
  int b = blockIdx.y;
  int r = blockIdx.x;
  uint lo = (uint)r << 11;     // 2048 bins per range block
  __shared__ uint lh[2048];
  __shared__ uint wr[4];
  int tid = threadIdx.x, lane = tid & 63, W = tid >> 6;
  for (int i = tid; i < 2048; i += 256) lh[i] = 0u;
  __syncthreads();
  const uint4* K = bkts4 + (size_t)b * (NN / 8);   // 8 ushorts per uint4
  uint inv = 0;
  for (int i = tid; i < NN / 8; i += 256) {
    uint4 v = K[i];
    uint q;
    q = v.x & 0xFFFFu;  { uint d = q - lo; if (d < 2048u) { if (q == 0xFFFFu) inv++; else atomicAdd(&lh[d], 1u); } }
    q = v.x >> 16;      { uint d = q - lo; if (d < 2048u) { if (q == 0xFFFFu) inv++; else atomicAdd(&lh[d], 1u); } }
    q = v.y & 0xFFFFu;  { uint d = q - lo; if (d < 2048u) { if (q == 0xFFFFu) inv++; else atomicAdd(&lh[d], 1u); } }
    q = v.y >> 16;      { uint d = q - lo; if (d < 2048u) { if (q == 0xFFFFu) inv++; else atomicAdd(&lh[d], 1u); } }
    q = v.z & 0xFFFFu;  { uint d = q - lo; if (d < 2048u) { if (q == 0xFFFFu) inv++; else atomicAdd(&lh[d], 1u); } }
    q = v.z >> 16;      { uint d = q - lo; if (d < 2048u) { if (q == 0xFFFFu) inv++; else atomicAdd(&lh[d], 1u); } }
    q = v.w & 0xFFFFu;  { uint d = q - lo; if (d < 2048u) { if (q == 0xFFFFu) inv++; else atomicAdd(&lh[d], 1u); } }
    q = v.w >> 16;      { uint d = q - lo; if (d < 2048u) { if (q == 0xFFFFu) inv++; else atomicAdd(&lh[d], 1u); } }
  }
  if (inv) atomicAdd(&lh[2047], inv);   // only block r=31 ever has inv>0
  __syncthreads();
  uint* H = hist1 + (size_t)b * 65536 + lo;
  uint s = 0;
  for (int i = tid; i < 2048; i += 256) { H[i] = lh[i]; s += lh[i]; }
  for (int off = 32; off > 0; off >>= 1) s += __shfl_xor(s, off);
  if (lane == 0) wr[W] = s;
  __syncthreads();
  if (tid == 0) rtot[b * 32 + r] = wr[0] + wr[1] + wr[2] + wr[3];
  uint* C = cnt + (size_t)b * ROWP + r * (ROWP / NRANGE);
  if (tid < ROWP / NRANGE) C[tid] = 0u;
}

// ---------- pass 2: per-range exclusive scan -> base[]; boundary -> hdr ----------
__global__ __launch_bounds__(256) void scan128(const uint* __restrict__ hist1,
                                               const uint* __restrict__ rtot,
                                               uint* __restrict__ base,
                                               uint* __restrict__ hdr,
                                               u64* __restrict__ validW) {
  int r = blockIdx.x, b = blockIdx.y;
  int tid = threadIdx.x, lane = tid & 63, W = tid >> 6;
  __shared__ uint wt[4];
  if (r == 0 && tid < 96) validW[(size_t)b * 96 + tid] = 0ull;
  uint lo = (uint)r << 11;
  uint rbase = 0, tot = 0;
  for (int k = 0; k < 32; ++k) {
    uint v = rtot[b * 32 + k];
    if (k < r) rbase += v;
    if (k == r) tot = v;
  }
  const uint* h = hist1 + (size_t)b * 65536 + lo;
  uint c[8], s = 0;
  for (int k = 0; k < 8; ++k) { c[k] = h[tid * 8 + k]; s += c[k]; }
  uint ps = s;
  for (int off = 1; off < 64; off <<= 1) {
    uint v = __shfl_up(ps, off);
    if (lane >= off) ps += v;
  }
  if (lane == 63) wt[W] = ps;
  __syncthreads();
  uint wbase = 0;
  for (int k = 0; k < 4; ++k) { if (k < W) wbase += wt[k]; }
  uint excl = rbase + wbase + ps - s;     // global exclusive before thread's bins
  uint run = excl;
  uint* bs = base + (size_t)b * 65536 + lo;
  for (int k = 0; k < 8; ++k) { bs[tid * 8 + k] = run; run += c[k]; }
  if (rbase < (uint)PRE && (uint)PRE <= rbase + tot) {
    uint cc = excl;
    for (int k = 0; k < 8; ++k) {
      uint hv = c[k];
      if (cc < (uint)PRE && (uint)PRE <= cc + hv) {
        hdr[0 + b] = lo + (uint)(tid * 8 + k);   // t1 boundary bucket
        hdr[4 + b] = cc + hv;                    // limit = cumulative through t1
      }
      cc += hv;
    }
  }
}

// ---------- pass 3: scatter full records of selected elems into bucket slots ----
__global__ void bucket_scatter(const uint* __restrict__ keyhi,
                               const ushort* __restrict__ bkts,
                               uint* __restrict__ base,
                               const uint* __restrict__ hdr,
                               const float4* __restrict__ props,
                               const float2* __restrict__ clsp,
                               u64* __restrict__ buck,
                               float4* __restrict__ buckBox,
                               float* __restrict__ buckSc,
                               ushort* __restrict__ buckBkt) {
  int b = blockIdx.y;
  int i = blockIdx.x * 256 + threadIdx.x;
  if (i >= NN) return;
  uint bk = bkts[(size_t)b * NN + i];
  if (bk <= hdr[0 + b]) {
    uint kh = keyhi[(size_t)b * NN + i];
    uint pos = atomicAdd(&base[(size_t)b * 65536 + bk], 1u);
    if (pos < SCAP) {
      buck[(size_t)b * SCAP + pos] = ((u64)kh << 32) | (uint)i;
      float4 p = props[(size_t)b * NN + i];
      float4 bx;
      bx.x = clipf(p.x, 800.0f); bx.y = clipf(p.y, 800.0f);
      bx.z = clipf(p.z, 800.0f); bx.w = clipf(p.w, 800.0f);
      buckBox[(size_t)b * SCAP + pos] = bx;
      buckSc [(size_t)b * SCAP + pos] = clsp[(size_t)b * NN + i].y;
      buckBkt[(size_t)b * SCAP + pos] = (ushort)bk;
    }
  }
}

// ---------- pass 4: exact rank -> copy record from slot to rank row ----------
// Mate loops now ~1-3 iterations (uniform buckets); all reads L2-hot.
__global__ void rank_scatter(const u64* __restrict__ buck,
                             const float4* __restrict__ buckBox,
                             const float* __restrict__ buckSc,
                             const ushort* __restrict__ buckBkt,
                             const uint* __restrict__ base,
                             const uint* __restrict__ hist,
                             const uint* __restrict__ hdr,
                             float4* __restrict__ boxes6k,
                             float* __restrict__ score6k,
                             float* __restrict__ area6k,
                             u64* __restrict__ validW) {
  int b = blockIdx.y;
  int s = blockIdx.x * 256 + threadIdx.x;
  uint limit = hdr[4 + b];
  if (s >= (int)limit) return;
  u64 v = buck[(size_t)b * SCAP + s];
  float4 bx = buckBox[(size_t)b * SCAP + s];
  float sc = buckSc[(size_t)b * SCAP + s];
  uint bkt = buckBkt[(size_t)b * SCAP + s];
  uint cntb = hist[(size_t)b * 65536 + bkt];
  uint b0 = base[(size_t)b * 65536 + bkt] - cntb;  // restore pre-scatter base
  uint r = b0;
  for (uint m = 0; m < cntb; ++m) {
    u64 w = buck[(size_t)b * SCAP + b0 + m];
    r += (w < v) ? 1u : 0u;                        // (key,idx) stable order
  }
  if (r >= (uint)PRE) return;
  float w = bx.z - bx.x, h = bx.w - bx.y;
  bool valid = (w >= 16.0f) && (h >= 16.0f);
  boxes6k[(size_t)b * ROWP + r] = bx;
  score6k[(size_t)b * ROWP + r] = sc;
  area6k [(size_t)b * ROWP + r] = fmaxf(w, 0.0f) * fmaxf(h, 0.0f);
  if (valid) atomicOr(&validW[(size_t)b * 96 + (r >> 6)], 1ull << (r & 63));
}

// ---------- shared sup tile body (exact division-free IoU test) ----------
// fl32(inter/un) > 0.7f  <=>  (double)inter >= M*(double)un,
// M = 0.7f + 2^-25 = 0x1.6666668p-1 (rounding midpoint; the tie
// rounds-to-even UP; 25b x 24b = 49 bits <= 53, conversions exact, un>0).
__device__ __forceinline__
void sup_tile(int b, int gb, int cw0, int wmax,
              const float4* boxes6k, const float* area6k, const u64* validW,
              uint* cnt, uint* list,
              float4* rbox, float* rar /* LDS, filled here */) {
  int w = threadIdx.x >> 6, lane = threadIdx.x & 63;
  if (threadIdx.x < 64) {
    rbox[lane] = boxes6k[(size_t)b * ROWP + gb * 64 + lane];
    rar[lane]  = area6k [(size_t)b * ROWP + gb * 64 + lane];
  }
  __syncthreads();
  u64 vmask = validW[(size_t)b * 96 + gb];

  int    cw[4];
  u64    rowsel[4], bits[4];
  float4 cbox[4];
  float  carea[4];
  #pragma unroll
  for (int k = 0; k < 4; ++k) {
    cw[k] = cw0 + 4 * k + w;            // wave w owns words cw0+w, +4, +8, +12
    int col = cw[k] * 64 + lane;
    int colc = col < (ROWP - 1) ? col : (ROWP - 1);
    cbox[k]  = boxes6k[(size_t)b * ROWP + colc];
    carea[k] = area6k [(size_t)b * ROWP + colc];
    rowsel[k] = (cw[k] > gb) ? vmask
              : ((cw[k] == gb && lane) ? (vmask & ((1ull << lane) - 1ull)) : 0ull);
    bits[k] = 0ull;
  }

  const double M = 0x1.6666668p-1;      // exact decision midpoint for (iou > 0.7f)
  #pragma unroll 4
  for (int r = 0; r < 64; ++r) {
    float4 rb = rbox[r];
    float  ra = rar[r];
    u64 m = 1ull << r;
    #pragma unroll
    for (int k = 0; k < 4; ++k) {
      float xx1 = fmaxf(rb.x, cbox[k].x), yy1 = fmaxf(rb.y, cbox[k].y);
      float xx2 = fminf(rb.z, cbox[k].z), yy2 = fminf(rb.w, cbox[k].w);
      float inter = fmaxf(xx2 - xx1, 0.0f) * fmaxf(yy2 - yy1, 0.0f);
      float un = fmaxf(ra + carea[k] - inter, 1e-9f);
      bits[k] |= ((double)inter >= M * (double)un) ? m : 0ull;
    }
  }

  int rbase = gb * 64;
  #pragma unroll
  for (int k = 0; k < 4; ++k) {
    if (cw[k] >= wmax) continue;
    u64 bt = bits[k] & rowsel[k];
    int col = cw[k] * 64 + lane;
    while (bt) {
      int r = __ffsll((long long)bt) - 1;
      bt &= bt - 1;
      uint pos = atomicAdd(&cnt[(size_t)b * ROWP + col], 1u);
      if (pos < KSUP) list[((size_t)b * ROWP + col) * KSUP + pos] = (uint)(rbase + r);
    }
  }
}

// ---------- pass 5a: suppressor lists within prefix [0, PREF) ----------
__global__ __launch_bounds__(256) void sup_build_pre(const float4* __restrict__ boxes6k,
                                                     const float* __restrict__ area6k,
                                                     const u64* __restrict__ validW,
                                                     uint* __restrict__ cnt,
                                                     uint* __restrict__ list) {
  int gb = blockIdx.y, b = blockIdx.z;
  int cw0 = blockIdx.x * WQ;            // 0 or 16
  if (cw0 + WQ - 1 < gb) return;        // fully below diagonal
  __shared__ float4 rbox[64];
  __shared__ float  rar[64];
  sup_tile(b, gb, cw0, PWRD, boxes6k, area6k, validW, cnt, list, rbox, rar);
}

// ---------- pass 5b: fallback — remaining tiles, only if !done[b] ----------
__global__ __launch_bounds__(256) void sup_build_full(const float4* __restrict__ boxes6k,
                                                      const float* __restrict__ area6k,
                                                      const u64* __restrict__ validW,
                                                      const uint* __restrict__ hdr,
                                                      uint* __restrict__ cnt,
                                                      uint* __restrict__ list) {
  int gb = blockIdx.y, b = blockIdx.z;
  if (hdr[8 + b]) return;               // prefix sufficed for this image
  int cw0 = blockIdx.x * WQ;
  if (cw0 + WQ - 1 < gb) return;        // fully below diagonal
  if (gb < PWRD && cw0 + WQ <= PWRD) return;  // prefix tiles already built
  __shared__ float4 rbox[64];
  __shared__ float  rar[64];
  sup_tile(b, gb, cw0, NWRD, boxes6k, area6k, validW, cnt, list, rbox, rar);
}

// ---------- pass 6a: prefix resolve + finalize; sets done[b] ----------
__global__ __launch_bounds__(1024) void resolve_pre(const uint* __restrict__ cnt,
                                                    const uint* __restrict__ list,
                                                    const u64* __restrict__ validW,
                                                    const float* __restrict__ score6k,
                                                    const float4* __restrict__ boxes6k,
                                                    uint* __restrict__ hdr,
                                                    float* __restrict__ out) {
  int b = blockIdx.x, tid = threadIdx.x;
  __shared__ u64 ALIVE[PWRD], DEC[PWRD], VW[PWRD];
  __shared__ int changed;
  if (tid < PWRD) {
    ALIVE[tid] = 0ull; DEC[tid] = 0ull;
    VW[tid] = validW[(size_t)b * 96 + tid];
  }
  __syncthreads();

  uint myCnt[2];
  #pragma unroll
  for (int r = 0; r < 2; ++r) {
    int j = tid + r * 1024;
    myCnt[r] = (j < PREF) ? cnt[(size_t)b * ROWP + j] : 0u;
  }
  #pragma unroll
  for (int r = 0; r < 2; ++r) {
    int j = tid + r * 1024;
    if (j >= PREF) continue;
    bool valid = (VW[j >> 6] >> (j & 63)) & 1ull;
    if (myCnt[r] == 0u || !valid) {
      atomicOr(&DEC[j >> 6], 1ull << (j & 63));
      if (valid) atomicOr(&ALIVE[j >> 6], 1ull << (j & 63));
    }
  }
  __syncthreads();

  while (true) {
    if (tid == 0) changed = 0;
    __syncthreads();
    int decJ[2]; bool decAlive[2];
    #pragma unroll
    for (int r = 0; r < 2; ++r) {
      decJ[r] = -1; decAlive[r] = false;
      int j = tid + r * 1024;
      if (j >= PREF || myCnt[r] == 0u) continue;
      if ((DEC[j >> 6] >> (j & 63)) & 1ull) continue;
      const uint* lj = list + ((size_t)b * ROWP + j) * KSUP;
      uint c = myCnt[r] < KSUP ? myCnt[r] : KSUP;
      bool anyAlive = false, pending = false;
      for (uint m = 0; m < c; ++m) {
        uint i = lj[m];
        bool ai = (ALIVE[i >> 6] >> (i & 63)) & 1ull;
        bool di = (DEC[i >> 6] >> (i & 63)) & 1ull;
        if (ai) { anyAlive = true; break; }
        if (!di) pending = true;
      }
      if (anyAlive)      { decJ[r] = j; decAlive[r] = false; }
      else if (!pending) { decJ[r] = j; decAlive[r] = true;  }
    }
    __syncthreads();
    bool any = false;
    #pragma unroll
    for (int r = 0; r < 2; ++r) {
      if (decJ[r] >= 0) {
        int j = decJ[r];
        if (decAlive[r]) atomicOr(&ALIVE[j >> 6], 1ull << (j & 63));
        atomicOr(&DEC[j >> 6], 1ull << (j & 63));
        any = true;
      }
    }
    if (any) atomicAdd(&changed, 1);
    __syncthreads();
    if (changed == 0) break;
  }

  __shared__ uint psum[PWRD + 1];
  if (tid == 0) {
    uint c = 0;
    for (int w = 0; w < PWRD; ++w) { psum[w] = c; c += (uint)__popcll(ALIVE[w]); }
    psum[PWRD] = c;
    hdr[8 + b] = (c >= (uint)POST) ? 1u : 0u;
  }
  __syncthreads();
  if (psum[PWRD] < (uint)POST) return;   // fallback path will produce output

  for (int q = tid; q < POST; q += 1024) out[(size_t)b * POST + q] = 0.0f;
  for (int t = tid; t < POST * 4; t += 1024) out[(size_t)BB * POST + (size_t)b * POST * 4 + t] = 0.0f;
  __syncthreads();
  for (int j = tid; j < PREF; j += 1024) {
    int w = j >> 6, bit = j & 63;
    u64 word = ALIVE[w];
    if ((word >> bit) & 1ull) {
      uint rank = psum[w] + (uint)__popcll(word & ((1ull << bit) - 1ull));
      if (rank < POST) {
        out[(size_t)b * POST + rank] = score6k[(size_t)b * ROWP + j];
        float4 bx = boxes6k[(size_t)b * ROWP + j];
        float* o = out + (size_t)BB * POST + ((size_t)b * POST + rank) * 4;
        o[0] = bx.x; o[1] = bx.y; o[2] = bx.z; o[3] = bx.w;
      }
    }
  }
}

// ---------- pass 6b: full resolve + finalize (only if !done[b]) ----------
__global__ __launch_bounds__(1024) void resolve_full(const uint* __restrict__ cnt,
                                                     const uint* __restrict__ list,
                                                     const u64* __restrict__ validW,
                                                     const float* __restrict__ score6k,
                                                     const float4* __restrict__ boxes6k,
                                                     const uint* __restrict__ hdr,
                                                     float* __restrict__ out) {
  int b = blockIdx.x, tid = threadIdx.x;
  if (hdr[8 + b]) return;               // prefix path already produced output
  __shared__ u64 ALIVE[96], DEC[96], VW[96];
  __shared__ int changed;
  if (tid < 96) {
    ALIVE[tid] = 0ull; DEC[tid] = 0ull;
    VW[tid] = validW[(size_t)b * 96 + tid];
  }
  __syncthreads();

  uint myCnt[6];
  #pragma unroll
  for (int r = 0; r < 6; ++r) {
    int j = tid + r * 1024;
    myCnt[r] = (j < PRE) ? cnt[(size_t)b * ROWP + j] : 0u;
  }
  #pragma unroll
  for (int r = 0; r < 6; ++r) {
    int j = tid + r * 1024;
    if (j >= PRE) continue;
    bool valid = (VW[j >> 6] >> (j & 63)) & 1ull;
    if (myCnt[r] == 0u || !valid) {
      atomicOr(&DEC[j >> 6], 1ull << (j & 63));
      if (valid) atomicOr(&ALIVE[j >> 6], 1ull << (j & 63));
    }
  }
  __syncthreads();

  while (true) {
    if (tid == 0) changed = 0;
    __syncthreads();
    int decJ[6]; bool decAlive[6];
    #pragma unroll
    for (int r = 0; r < 6; ++r) {
      decJ[r] = -1; decAlive[r] = false;
      int j = tid + r * 1024;
      if (j >= PRE || myCnt[r] == 0u) continue;
      if ((DEC[j >> 6] >> (j & 63)) & 1ull) continue;
      const uint* lj = list + ((size_t)b * ROWP + j) * KSUP;
      uint c = myCnt[r] < KSUP ? myCnt[r] : KSUP;
      bool anyAlive = false, pending = false;
      for (uint m = 0; m < c; ++m) {
        uint i = lj[m];
        bool ai = (ALIVE[i >> 6] >> (i & 63)) & 1ull;
        bool di = (DEC[i >> 6] >> (i & 63)) & 1ull;
        if (ai) { anyAlive = true; break; }
        if (!di) pending = true;
      }
      if (anyAlive)      { decJ[r] = j; decAlive[r] = false; }
      else if (!pending) { decJ[r] = j; decAlive[r] = true;  }
    }
    __syncthreads();
    bool any = false;
    #pragma unroll
    for (int r = 0; r < 6; ++r) {
      if (decJ[r] >= 0) {
        int j = decJ[r];
        if (decAlive[r]) atomicOr(&ALIVE[j >> 6], 1ull << (j & 63));
        atomicOr(&DEC[j >> 6], 1ull << (j & 63));
        any = true;
      }
    }
    if (any) atomicAdd(&changed, 1);
    __syncthreads();
    if (changed == 0) break;
  }

  __shared__ uint psum[NWRD + 1];
  if (tid == 0) {
    uint c = 0;
    for (int w = 0; w < NWRD; ++w) { psum[w] = c; c += (uint)__popcll(ALIVE[w]); }
    psum[NWRD] = c;
  }
  __syncthreads();
  for (int q = tid; q < POST; q += 1024) out[(size_t)b * POST + q] = 0.0f;
  for (int t = tid; t < POST * 4; t += 1024) out[(size_t)BB * POST + (size_t)b * POST * 4 + t] = 0.0f;
  __syncthreads();
  for (int j = tid; j < PRE; j += 1024) {
    int w = j >> 6, bit = j & 63;
    u64 word = ALIVE[w];
    if ((word >> bit) & 1ull) {
      uint rank = psum[w] + (uint)__popcll(word & ((1ull << bit) - 1ull));
      if (rank < POST) {
        out[(size_t)b * POST + rank] = score6k[(size_t)b * ROWP + j];
        float4 bx = boxes6k[(size_t)b * ROWP + j];
        float* o = out + (size_t)BB * POST + ((size_t)b * POST + rank) * 4;
        o[0] = bx.x; o[1] = bx.y; o[2] = bx.z; o[3] = bx.w;
      }
    }
  }
}

extern "C" void kernel_launch(void* const* d_in, const int* in_sizes, int n_in,
                              void* d_out, int out_size, void* d_ws, size_t ws_size,
                              hipStream_t stream) {
  const float4* props = (const float4*)d_in[0];
  const float2* clsp  = (const float2*)d_in[1];
  float* out = (float*)d_out;
  char* ws = (char*)d_ws;

  uint*   hdr     = (uint*)(ws + OFF_HDR);
  uint*   rtot    = (uint*)(ws + OFF_RTOT);
  uint*   cnt     = (uint*)(ws + OFF_CNT);
  uint*   hist1   = (uint*)(ws + OFF_H1);
  uint*   base    = (uint*)(ws + OFF_BASE);
  uint*   keyhi   = (uint*)(ws + OFF_KEY);
  ushort* bkts    = (ushort*)(ws + OFF_BKT);
  u64*    buck    = (u64*) (ws + OFF_BUCK);
  float4* buckBox = (float4*)(ws + OFF_BBOX);
  float*  buckSc  = (float*)(ws + OFF_BSC);
  ushort* buckBkt = (ushort*)(ws + OFF_BBKT);
  uint*   list    = (uint*)(ws + OFF_LIST);
  float4* boxes6k = (float4*)(ws + OFF_BOX);
  float*  score6k = (float*)(ws + OFF_SCO);
  float*  area6k  = (float*)(ws + OFF_AREA);
  u64*    validW  = (u64*) (ws + OFF_VAL);

  dim3 gN((NN + 255) / 256, BB);
  keys_only<<<gN, 256, 0, stream>>>(props, clsp, keyhi, bkts);
  hist_range<<<dim3(NRANGE, BB), 256, 0, stream>>>((const uint4*)bkts, hist1, rtot, cnt);
  scan128<<<dim3(NRANGE, BB), 256, 0, stream>>>(hist1, rtot, base, hdr, validW);
  bucket_scatter<<<gN, 256, 0, stream>>>(keyhi, bkts, base, hdr, props, clsp,
                                         buck, buckBox, buckSc, buckBkt);
  rank_scatter<<<dim3(SCAP / 256, BB), 256, 0, stream>>>(buck, buckBox, buckSc, buckBkt,
                                                         base, hist1, hdr,
                                                         boxes6k, score6k, area6k, validW);
  sup_build_pre<<<dim3(2, PWRD, BB), 256, 0, stream>>>(boxes6k, area6k, validW, cnt, list);
  resolve_pre<<<BB, 1024, 0, stream>>>(cnt, list, validW, score6k, boxes6k, hdr, out);
  sup_build_full<<<dim3((NWRD + WQ - 1) / WQ, NWRD, BB), 256, 0, stream>>>(boxes6k, area6k,
                                                                           validW, hdr, cnt, list);
  resolve_full<<<BB, 1024, 0, stream>>>(cnt, list, validW, score6k, boxes6k, hdr, out);
}

// Round 19
// 92.482 us; speedup vs baseline: 1.7798x; 1.0338x over previous
//
#include <hip/hip_runtime.h>
#include <hip/hip_bf16.h>
#include <math.h>

typedef unsigned int uint;
typedef unsigned short ushort;
typedef unsigned long long u64;

#define BB 4
#define NN 100000
#define PRE 6000
#define POST 1000
#define NWRD 94          // 6000/64 rounded up
#define PREF 2048        // NMS prefix (exact if >=1000 kept inside; else in-block fallback)
#define PWRD 32          // PREF/64
#define SCAP 8192        // bucketed capacity
#define ROWP 6016        // padded rows/cols
#define KSUP 64          // max suppressors tracked per box
#define NRANGE 32        // hist ranges per image (2048 bins each)
#define WQ 16            // col-words per sup_build block

// ---- workspace layout (bytes) ----
constexpr size_t OFF_HDR   = 0;                                    // uints: t1[4], limit[4]
constexpr size_t OFF_RTOT  = 64;                                   // 128 uints: per-(b,range) totals
constexpr size_t OFF_CNT   = 1024;                                 // BB*ROWP*4 (zeroed by hist_range)
constexpr size_t OFF_H1    = OFF_CNT + (size_t)BB*ROWP*4;          // hist1: 1MB (fully overwritten)
constexpr size_t OFF_BASE  = OFF_H1  + (size_t)BB*65536*4;         // base:  1MB (fully overwritten)
constexpr size_t OFF_BKT   = OFF_BASE+ (size_t)BB*65536*4;         // bkts:  BB*NN*2 (ushort)
constexpr size_t OFF_BUCK  = OFF_BKT + (size_t)BB*NN*2;            // keys:  BB*SCAP*8
constexpr size_t OFF_BBOX  = OFF_BUCK+ (size_t)BB*SCAP*8;          // boxes: BB*SCAP*16
constexpr size_t OFF_BSC   = OFF_BBOX+ (size_t)BB*SCAP*16;         // score: BB*SCAP*4
constexpr size_t OFF_BBKT  = OFF_BSC + (size_t)BB*SCAP*4;          // bkt:   BB*SCAP*2
constexpr size_t OFF_LIST  = OFF_BBKT+ (size_t)BB*SCAP*2;          // BB*ROWP*KSUP*4
constexpr size_t OFF_BOX   = OFF_LIST+ (size_t)BB*ROWP*KSUP*4;
constexpr size_t OFF_SCO   = OFF_BOX + (size_t)BB*ROWP*16;
constexpr size_t OFF_AREA  = OFF_SCO + (size_t)BB*ROWP*4;
constexpr size_t OFF_VAL   = OFF_AREA+ (size_t)BB*ROWP*4;          // validW (zeroed by scan128)

__device__ __forceinline__ float clipf(float v, float hi) {
  return fminf(fmaxf(v, 0.0f), hi);
}

// Uniform, weakly key-monotone bucket map (exactness: within-bucket ranking is
// by the exact (key,idx) compare, so any weakly monotone coarsening is exact).
__device__ __forceinline__ uint bucket_of(float s, bool valid) {
  if (!valid) return 65535u;
  float t = fminf(fmaxf(s, 0.0f), 1.0f);
  uint q = (uint)(t * 65536.0f);
  q = q > 65535u ? 65535u : q;
  return 65535u - q;                    // higher score -> lower bucket
}

// ---------- pass 1a: buckets only (pure streaming, no atomics) ----------
__global__ void bkts_only(const float4* __restrict__ props,
                          const float2* __restrict__ clsp,
                          ushort* __restrict__ bkts) {
  int b = blockIdx.y;
  int i = blockIdx.x * 256 + threadIdx.x;
  if (i >= NN) return;
  float4 p = props[(size_t)b * NN + i];
  float x1 = clipf(p.x, 800.0f), y1 = clipf(p.y, 800.0f);
  float x2 = clipf(p.z, 800.0f), y2 = clipf(p.w, 800.0f);
  bool valid = ((x2 - x1) >= 16.0f) && ((y2 - y1) >= 16.0f);
  float s  = clsp[(size_t)b * NN + i].y;
  bkts[(size_t)b * NN + i] = (ushort)bucket_of(s, valid);
}

// ---------- pass 1b: range-partitioned LDS histogram over bkts ----------
__global__ __launch_bounds__(256) void hist_range(const uint4* __restrict__ bkts4,
                                                  uint* __restrict__ hist1,
                                                  uint* __restrict__ rtot,
                                                  uint* __restrict__ cnt) {
  int b = blockIdx.y;
  int r = blockIdx.x;
  uint lo = (uint)r << 11;     // 2048 bins per range block
  __shared__ uint lh[2048];
  __shared__ uint wr[4];
  int tid = threadIdx.x, lane = tid & 63, W = tid >> 6;
  for (int i = tid; i < 2048; i += 256) lh[i] = 0u;
  __syncthreads();
  const uint4* K = bkts4 + (size_t)b * (NN / 8);   // 8 ushorts per uint4
  uint inv = 0;
  for (int i = tid; i < NN / 8; i += 256) {
    uint4 v = K[i];
    uint q;
    q = v.x & 0xFFFFu;  { uint d = q - lo; if (d < 2048u) { if (q == 0xFFFFu) inv++; else atomicAdd(&lh[d], 1u); } }
    q = v.x >> 16;      { uint d = q - lo; if (d < 2048u) { if (q == 0xFFFFu) inv++; else atomicAdd(&lh[d], 1u); } }
    q = v.y & 0xFFFFu;  { uint d = q - lo; if (d < 2048u) { if (q == 0xFFFFu) inv++; else atomicAdd(&lh[d], 1u); } }
    q = v.y >> 16;      { uint d = q - lo; if (d < 2048u) { if (q == 0xFFFFu) inv++; else atomicAdd(&lh[d], 1u); } }
    q = v.z & 0xFFFFu;  { uint d = q - lo; if (d < 2048u) { if (q == 0xFFFFu) inv++; else atomicAdd(&lh[d], 1u); } }
    q = v.z >> 16;      { uint d = q - lo; if (d < 2048u) { if (q == 0xFFFFu) inv++; else atomicAdd(&lh[d], 1u); } }
    q = v.w & 0xFFFFu;  { uint d = q - lo; if (d < 2048u) { if (q == 0xFFFFu) inv++; else atomicAdd(&lh[d], 1u); } }
    q = v.w >> 16;      { uint d = q - lo; if (d < 2048u) { if (q == 0xFFFFu) inv++; else atomicAdd(&lh[d], 1u); } }
  }
  if (inv) atomicAdd(&lh[2047], inv);   // only block r=31 ever has inv>0
  __syncthreads();
  uint* H = hist1 + (size_t)b * 65536 + lo;
  uint s = 0;
  for (int i = tid; i < 2048; i += 256) { H[i] = lh[i]; s += lh[i]; }
  for (int off = 32; off > 0; off >>= 1) s += __shfl_xor(s, off);
  if (lane == 0) wr[W] = s;
  __syncthreads();
  if (tid == 0) rtot[b * 32 + r] = wr[0] + wr[1] + wr[2] + wr[3];
  uint* C = cnt + (size_t)b * ROWP + r * (ROWP / NRANGE);
  if (tid < ROWP / NRANGE) C[tid] = 0u;
}

// ---------- pass 2: per-range exclusive scan -> base[]; boundary -> hdr ----------
__global__ __launch_bounds__(256) void scan128(const uint* __restrict__ hist1,
                                               const uint* __restrict__ rtot,
                                               uint* __restrict__ base,
                                               uint* __restrict__ hdr,
                                               u64* __restrict__ validW) {
  int r = blockIdx.x, b = blockIdx.y;
  int tid = threadIdx.x, lane = tid & 63, W = tid >> 6;
  __shared__ uint wt[4];
  if (r == 0 && tid < 96) validW[(size_t)b * 96 + tid] = 0ull;
  uint lo = (uint)r << 11;
  uint rbase = 0, tot = 0;
  for (int k = 0; k < 32; ++k) {
    uint v = rtot[b * 32 + k];
    if (k < r) rbase += v;
    if (k == r) tot = v;
  }
  const uint* h = hist1 + (size_t)b * 65536 + lo;
  uint c[8], s = 0;
  for (int k = 0; k < 8; ++k) { c[k] = h[tid * 8 + k]; s += c[k]; }
  uint ps = s;
  for (int off = 1; off < 64; off <<= 1) {
    uint v = __shfl_up(ps, off);
    if (lane >= off) ps += v;
  }
  if (lane == 63) wt[W] = ps;
  __syncthreads();
  uint wbase = 0;
  for (int k = 0; k < 4; ++k) { if (k < W) wbase += wt[k]; }
  uint excl = rbase + wbase + ps - s;     // global exclusive before thread's bins
  uint run = excl;
  uint* bs = base + (size_t)b * 65536 + lo;
  for (int k = 0; k < 8; ++k) { bs[tid * 8 + k] = run; run += c[k]; }
  if (rbase < (uint)PRE && (uint)PRE <= rbase + tot) {
    uint cc = excl;
    for (int k = 0; k < 8; ++k) {
      uint hv = c[k];
      if (cc < (uint)PRE && (uint)PRE <= cc + hv) {
        hdr[0 + b] = lo + (uint)(tid * 8 + k);   // t1 boundary bucket
        hdr[4 + b] = cc + hv;                    // limit = cumulative through t1
      }
      cc += hv;
    }
  }
}

// ---------- pass 3: scatter full records (key recomputed inline) ----------
__global__ void bucket_scatter(const ushort* __restrict__ bkts,
                               uint* __restrict__ base,
                               const uint* __restrict__ hdr,
                               const float4* __restrict__ props,
                               const float2* __restrict__ clsp,
                               u64* __restrict__ buck,
                               float4* __restrict__ buckBox,
                               float* __restrict__ buckSc,
                               ushort* __restrict__ buckBkt) {
  int b = blockIdx.y;
  int i = blockIdx.x * 256 + threadIdx.x;
  if (i >= NN) return;
  uint bk = bkts[(size_t)b * NN + i];
  if (bk <= hdr[0 + b]) {
    uint pos = atomicAdd(&base[(size_t)b * 65536 + bk], 1u);
    if (pos < SCAP) {
      float4 p = props[(size_t)b * NN + i];
      float4 bx;
      bx.x = clipf(p.x, 800.0f); bx.y = clipf(p.y, 800.0f);
      bx.z = clipf(p.z, 800.0f); bx.w = clipf(p.w, 800.0f);
      bool valid = ((bx.z - bx.x) >= 16.0f) && ((bx.w - bx.y) >= 16.0f);
      float s = clsp[(size_t)b * NN + i].y;
      float sm = valid ? s : -INFINITY;
      uint u = __float_as_uint(sm);
      u = (u & 0x80000000u) ? ~u : (u | 0x80000000u);  // monotonic map
      uint kh = ~u;                                     // ascending == DESC score
      buck[(size_t)b * SCAP + pos] = ((u64)kh << 32) | (uint)i;
      buckBox[(size_t)b * SCAP + pos] = bx;
      buckSc [(size_t)b * SCAP + pos] = s;
      buckBkt[(size_t)b * SCAP + pos] = (ushort)bk;
    }
  }
}

// ---------- pass 4: exact rank -> copy record from slot to rank row ----------
__global__ void rank_scatter(const u64* __restrict__ buck,
                             const float4* __restrict__ buckBox,
                             const float* __restrict__ buckSc,
                             const ushort* __restrict__ buckBkt,
                             const uint* __restrict__ base,
                             const uint* __restrict__ hist,
                             const uint* __restrict__ hdr,
                             float4* __restrict__ boxes6k,
                             float* __restrict__ score6k,
                             float* __restrict__ area6k,
                             u64* __restrict__ validW) {
  int b = blockIdx.y;
  int s = blockIdx.x * 256 + threadIdx.x;
  uint limit = hdr[4 + b];
  if (s >= (int)limit) return;
  u64 v = buck[(size_t)b * SCAP + s];
  float4 bx = buckBox[(size_t)b * SCAP + s];
  float sc = buckSc[(size_t)b * SCAP + s];
  uint bkt = buckBkt[(size_t)b * SCAP + s];
  uint cntb = hist[(size_t)b * 65536 + bkt];
  uint b0 = base[(size_t)b * 65536 + bkt] - cntb;  // restore pre-scatter base
  uint r = b0;
  for (uint m = 0; m < cntb; ++m) {
    u64 w = buck[(size_t)b * SCAP + b0 + m];
    r += (w < v) ? 1u : 0u;                        // (key,idx) stable order
  }
  if (r >= (uint)PRE) return;
  float w = bx.z - bx.x, h = bx.w - bx.y;
  bool valid = (w >= 16.0f) && (h >= 16.0f);
  boxes6k[(size_t)b * ROWP + r] = bx;
  score6k[(size_t)b * ROWP + r] = sc;
  area6k [(size_t)b * ROWP + r] = fmaxf(w, 0.0f) * fmaxf(h, 0.0f);
  if (valid) atomicOr(&validW[(size_t)b * 96 + (r >> 6)], 1ull << (r & 63));
}

// ---------- shared sup tile body (exact division-free IoU test) ----------
// fl32(inter/un) > 0.7f  <=>  (double)inter >= M*(double)un,
// M = 0.7f + 2^-25 = 0x1.6666668p-1 (rounding midpoint; the tie
// rounds-to-even UP; 25b x 24b = 49 bits <= 53, conversions exact, un>0).
__device__ __forceinline__
void sup_tile(int b, int gb, int cw0, int wmax,
              const float4* boxes6k, const float* area6k, const u64* validW,
              uint* cnt, uint* list,
              float4* rbox, float* rar /* LDS, filled here */) {
  int w = threadIdx.x >> 6, lane = threadIdx.x & 63;
  if (threadIdx.x < 64) {
    rbox[lane] = boxes6k[(size_t)b * ROWP + gb * 64 + lane];
    rar[lane]  = area6k [(size_t)b * ROWP + gb * 64 + lane];
  }
  __syncthreads();
  u64 vmask = validW[(size_t)b * 96 + gb];

  int    cw[4];
  u64    rowsel[4], bits[4];
  float4 cbox[4];
  float  carea[4];
  #pragma unroll
  for (int k = 0; k < 4; ++k) {
    cw[k] = cw0 + 4 * k + w;            // wave w owns words cw0+w, +4, +8, +12
    int col = cw[k] * 64 + lane;
    int colc = col < (ROWP - 1) ? col : (ROWP - 1);
    cbox[k]  = boxes6k[(size_t)b * ROWP + colc];
    carea[k] = area6k [(size_t)b * ROWP + colc];
    rowsel[k] = (cw[k] > gb) ? vmask
              : ((cw[k] == gb && lane) ? (vmask & ((1ull << lane) - 1ull)) : 0ull);
    bits[k] = 0ull;
  }

  const double M = 0x1.6666668p-1;      // exact decision midpoint for (iou > 0.7f)
  #pragma unroll 4
  for (int r = 0; r < 64; ++r) {
    float4 rb = rbox[r];
    float  ra = rar[r];
    u64 m = 1ull << r;
    #pragma unroll
    for (int k = 0; k < 4; ++k) {
      float xx1 = fmaxf(rb.x, cbox[k].x), yy1 = fmaxf(rb.y, cbox[k].y);
      float xx2 = fminf(rb.z, cbox[k].z), yy2 = fminf(rb.w, cbox[k].w);
      float inter = fmaxf(xx2 - xx1, 0.0f) * fmaxf(yy2 - yy1, 0.0f);
      float un = fmaxf(ra + carea[k] - inter, 1e-9f);
      bits[k] |= ((double)inter >= M * (double)un) ? m : 0ull;
    }
  }

  int rbase = gb * 64;
  #pragma unroll
  for (int k = 0; k < 4; ++k) {
    if (cw[k] >= wmax) continue;
    u64 bt = bits[k] & rowsel[k];
    int col = cw[k] * 64 + lane;
    while (bt) {
      int r = __ffsll((long long)bt) - 1;
      bt &= bt - 1;
      uint pos = atomicAdd(&cnt[(size_t)b * ROWP + col], 1u);
      if (pos < KSUP) list[((size_t)b * ROWP + col) * KSUP + pos] = (uint)(rbase + r);
    }
  }
}

// ---------- pass 5: suppressor lists within prefix [0, PREF) ----------
__global__ __launch_bounds__(256) void sup_build_pre(const float4* __restrict__ boxes6k,
                                                     const float* __restrict__ area6k,
                                                     const u64* __restrict__ validW,
                                                     uint* __restrict__ cnt,
                                                     uint* __restrict__ list) {
  int gb = blockIdx.y, b = blockIdx.z;
  int cw0 = blockIdx.x * WQ;            // 0 or 16
  if (cw0 + WQ - 1 < gb) return;        // fully below diagonal
  __shared__ float4 rbox[64];
  __shared__ float  rar[64];
  sup_tile(b, gb, cw0, PWRD, boxes6k, area6k, validW, cnt, list, rbox, rar);
}

// ---------- pass 6: prefix resolve + finalize, with exact in-block fallback ----
// Fast path (always on this data): >=1000 kept within the 2048-prefix.
// Fallback (exact, never taken here): this block builds the remaining
// suppressor tiles itself, then resolves over the full 6000.
__global__ __launch_bounds__(1024) void resolve_pre(uint* __restrict__ cnt,
                                                    uint* __restrict__ list,
                                                    const u64* __restrict__ validW,
                                                    const float* __restrict__ score6k,
                                                    const float4* __restrict__ boxes6k,
                                                    const float* __restrict__ area6k,
                                                    float* __restrict__ out) {
  int b = blockIdx.x, tid = threadIdx.x, lane = tid & 63, wv = tid >> 6;
  __shared__ u64 ALIVE[96], DEC[96], VW[96];
  __shared__ int changed;
  __shared__ uint psum[NWRD + 1];
  __shared__ float4 rbox[64];
  __shared__ float  rar[64];
  if (tid < 96) {
    ALIVE[tid] = 0ull; DEC[tid] = 0ull;
    VW[tid] = validW[(size_t)b * 96 + tid];
  }
  __syncthreads();

  // ===== prefix resolve =====
  uint myCnt[2];
  #pragma unroll
  for (int r = 0; r < 2; ++r) {
    int j = tid + r * 1024;
    myCnt[r] = (j < PREF) ? cnt[(size_t)b * ROWP + j] : 0u;
  }
  #pragma unroll
  for (int r = 0; r < 2; ++r) {
    int j = tid + r * 1024;
    if (j >= PREF) continue;
    bool valid = (VW[j >> 6] >> (j & 63)) & 1ull;
    if (myCnt[r] == 0u || !valid) {
      atomicOr(&DEC[j >> 6], 1ull << (j & 63));
      if (valid) atomicOr(&ALIVE[j >> 6], 1ull << (j & 63));
    }
  }
  __syncthreads();
  while (true) {
    if (tid == 0) changed = 0;
    __syncthreads();
    int decJ[2]; bool decAlive[2];
    #pragma unroll
    for (int r = 0; r < 2; ++r) {
      decJ[r] = -1; decAlive[r] = false;
      int j = tid + r * 1024;
      if (j >= PREF || myCnt[r] == 0u) continue;
      if ((DEC[j >> 6] >> (j & 63)) & 1ull) continue;
      const uint* lj = list + ((size_t)b * ROWP + j) * KSUP;
      uint c = myCnt[r] < KSUP ? myCnt[r] : KSUP;
      bool anyAlive = false, pending = false;
      for (uint m = 0; m < c; ++m) {
        uint i = lj[m];
        bool ai = (ALIVE[i >> 6] >> (i & 63)) & 1ull;
        bool di = (DEC[i >> 6] >> (i & 63)) & 1ull;
        if (ai) { anyAlive = true; break; }
        if (!di) pending = true;
      }
      if (anyAlive)      { decJ[r] = j; decAlive[r] = false; }
      else if (!pending) { decJ[r] = j; decAlive[r] = true;  }
    }
    __syncthreads();
    bool any = false;
    #pragma unroll
    for (int r = 0; r < 2; ++r) {
      if (decJ[r] >= 0) {
        int j = decJ[r];
        if (decAlive[r]) atomicOr(&ALIVE[j >> 6], 1ull << (j & 63));
        atomicOr(&DEC[j >> 6], 1ull << (j & 63));
        any = true;
      }
    }
    if (any) atomicAdd(&changed, 1);
    __syncthreads();
    if (changed == 0) break;
  }

  if (tid == 0) {
    uint c = 0;
    for (int w = 0; w < PWRD; ++w) { psum[w] = c; c += (uint)__popcll(ALIVE[w]); }
    psum[PWRD] = c;
  }
  __syncthreads();

  if (psum[PWRD] >= (uint)POST) {
    // ===== fast path: finalize from prefix =====
    for (int q = tid; q < POST; q += 1024) out[(size_t)b * POST + q] = 0.0f;
    for (int t = tid; t < POST * 4; t += 1024) out[(size_t)BB * POST + (size_t)b * POST * 4 + t] = 0.0f;
    __syncthreads();
    for (int j = tid; j < PREF; j += 1024) {
      int w = j >> 6, bit = j & 63;
      u64 word = ALIVE[w];
      if ((word >> bit) & 1ull) {
        uint rank = psum[w] + (uint)__popcll(word & ((1ull << bit) - 1ull));
        if (rank < POST) {
          out[(size_t)b * POST + rank] = score6k[(size_t)b * ROWP + j];
          float4 bx = boxes6k[(size_t)b * ROWP + j];
          float* o = out + (size_t)BB * POST + ((size_t)b * POST + rank) * 4;
          o[0] = bx.x; o[1] = bx.y; o[2] = bx.z; o[3] = bx.w;
        }
      }
    }
    return;
  }

  // ===== exact fallback (never taken on this data) =====
  // 1) build remaining suppressor lists (all tiles except prefix x prefix)
  const double M = 0x1.6666668p-1;
  for (int gb = 0; gb < NWRD; ++gb) {
    __syncthreads();
    if (tid < 64) {
      rbox[tid] = boxes6k[(size_t)b * ROWP + gb * 64 + tid];
      rar[tid]  = area6k [(size_t)b * ROWP + gb * 64 + tid];
    }
    __syncthreads();
    u64 vmask = VW[gb];
    for (int cw = gb + wv; cw < NWRD; cw += 16) {
      if (gb < PWRD && cw < PWRD) continue;   // prefix pairs already built
      int col = cw * 64 + lane;
      int colc = col < (ROWP - 1) ? col : (ROWP - 1);
      float4 c = boxes6k[(size_t)b * ROWP + colc];
      float ca = area6k[(size_t)b * ROWP + colc];
      u64 rowsel = (cw > gb) ? vmask
                 : (lane ? (vmask & ((1ull << lane) - 1ull)) : 0ull);
      u64 bits = 0;
      #pragma unroll 4
      for (int r = 0; r < 64; ++r) {
        float4 rb = rbox[r];
        float xx1 = fmaxf(rb.x, c.x), yy1 = fmaxf(rb.y, c.y);
        float xx2 = fminf(rb.z, c.z), yy2 = fminf(rb.w, c.w);
        float inter = fmaxf(xx2 - xx1, 0.0f) * fmaxf(yy2 - yy1, 0.0f);
        float un = fmaxf(rar[r] + ca - inter, 1e-9f);
        bits |= ((double)inter >= M * (double)un) ? (1ull << r) : 0ull;
      }
      bits &= rowsel;
      while (bits) {
        int r = __ffsll((long long)bits) - 1;
        bits &= bits - 1;
        uint pos = atomicAdd(&cnt[(size_t)b * ROWP + col], 1u);
        if (pos < KSUP) list[((size_t)b * ROWP + col) * KSUP + pos] = (uint)(gb * 64 + r);
      }
    }
  }
  __syncthreads();

  // 2) full resolve over [0, PRE)
  if (tid < 96) { ALIVE[tid] = 0ull; DEC[tid] = 0ull; }
  __syncthreads();
  uint myCnt6[6];
  #pragma unroll
  for (int r = 0; r < 6; ++r) {
    int j = tid + r * 1024;
    myCnt6[r] = (j < PRE) ? cnt[(size_t)b * ROWP + j] : 0u;
  }
  #pragma unroll
  for (int r = 0; r < 6; ++r) {
    int j = tid + r * 1024;
    if (j >= PRE) continue;
    bool valid = (VW[j >> 6] >> (j & 63)) & 1ull;
    if (myCnt6[r] == 0u || !valid) {
      atomicOr(&DEC[j >> 6], 1ull << (j & 63));
      if (valid) atomicOr(&ALIVE[j >> 6], 1ull << (j & 63));
    }
  }
  __syncthreads();
  while (true) {
    if (tid == 0) changed = 0;
    __syncthreads();
    int decJ[6]; bool decAlive[6];
    #pragma unroll
    for (int r = 0; r < 6; ++r) {
      decJ[r] = -1; decAlive[r] = false;
      int j = tid + r * 1024;
      if (j >= PRE || myCnt6[r] == 0u) continue;
      if ((DEC[j >> 6] >> (j & 63)) & 1ull) continue;
      const uint* lj = list + ((size_t)b * ROWP + j) * KSUP;
      uint c = myCnt6[r] < KSUP ? myCnt6[r] : KSUP;
      bool anyAlive = false, pending = false;
      for (uint m = 0; m < c; ++m) {
        uint i = lj[m];
        bool ai = (ALIVE[i >> 6] >> (i & 63)) & 1ull;
        bool di = (DEC[i >> 6] >> (i & 63)) & 1ull;
        if (ai) { anyAlive = true; break; }
        if (!di) pending = true;
      }
      if (anyAlive)      { decJ[r] = j; decAlive[r] = false; }
      else if (!pending) { decJ[r] = j; decAlive[r] = true;  }
    }
    __syncthreads();
    bool any = false;
    #pragma unroll
    for (int r = 0; r < 6; ++r) {
      if (decJ[r] >= 0) {
        int j = decJ[r];
        if (decAlive[r]) atomicOr(&ALIVE[j >> 6], 1ull << (j & 63));
        atomicOr(&DEC[j >> 6], 1ull << (j & 63));
        any = true;
      }
    }
    if (any) atomicAdd(&changed, 1);
    __syncthreads();
    if (changed == 0) break;
  }

  if (tid == 0) {
    uint c = 0;
    for (int w = 0; w < NWRD; ++w) { psum[w] = c; c += (uint)__popcll(ALIVE[w]); }
    psum[NWRD] = c;
  }
  __syncthreads();
  for (int q = tid; q < POST; q += 1024) out[(size_t)b * POST + q] = 0.0f;
  for (int t = tid; t < POST * 4; t += 1024) out[(size_t)BB * POST + (size_t)b * POST * 4 + t] = 0.0f;
  __syncthreads();
  for (int j = tid; j < PRE; j += 1024) {
    int w = j >> 6, bit = j & 63;
    u64 word = ALIVE[w];
    if ((word >> bit) & 1ull) {
      uint rank = psum[w] + (uint)__popcll(word & ((1ull << bit) - 1ull));
      if (rank < POST) {
        out[(size_t)b * POST + rank] = score6k[(size_t)b * ROWP + j];
        float4 bx = boxes6k[(size_t)b * ROWP + j];
        float* o = out + (size_t)BB * POST + ((size_t)b * POST + rank) * 4;
        o[0] = bx.x; o[1] = bx.y; o[2] = bx.z; o[3] = bx.w;
      }
    }
  }
}

extern "C" void kernel_launch(void* const* d_in, const int* in_sizes, int n_in,
                              void* d_out, int out_size, void* d_ws, size_t ws_size,
                              hipStream_t stream) {
  const float4* props = (const float4*)d_in[0];
  const float2* clsp  = (const float2*)d_in[1];
  float* out = (float*)d_out;
  char* ws = (char*)d_ws;

  uint*   hdr     = (uint*)(ws + OFF_HDR);
  uint*   rtot    = (uint*)(ws + OFF_RTOT);
  uint*   cnt     = (uint*)(ws + OFF_CNT);
  uint*   hist1   = (uint*)(ws + OFF_H1);
  uint*   base    = (uint*)(ws + OFF_BASE);
  ushort* bkts    = (ushort*)(ws + OFF_BKT);
  u64*    buck    = (u64*) (ws + OFF_BUCK);
  float4* buckBox = (float4*)(ws + OFF_BBOX);
  float*  buckSc  = (float*)(ws + OFF_BSC);
  ushort* buckBkt = (ushort*)(ws + OFF_BBKT);
  uint*   list    = (uint*)(ws + OFF_LIST);
  float4* boxes6k = (float4*)(ws + OFF_BOX);
  float*  score6k = (float*)(ws + OFF_SCO);
  float*  area6k  = (float*)(ws + OFF_AREA);
  u64*    validW  = (u64*) (ws + OFF_VAL);

  dim3 gN((NN + 255) / 256, BB);
  bkts_only<<<gN, 256, 0, stream>>>(props, clsp, bkts);
  hist_range<<<dim3(NRANGE, BB), 256, 0, stream>>>((const uint4*)bkts, hist1, rtot, cnt);
  scan128<<<dim3(NRANGE, BB), 256, 0, stream>>>(hist1, rtot, base, hdr, validW);
  bucket_scatter<<<gN, 256, 0, stream>>>(bkts, base, hdr, props, clsp,
                                         buck, buckBox, buckSc, buckBkt);
  rank_scatter<<<dim3(SCAP / 256, BB), 256, 0, stream>>>(buck, buckBox, buckSc, buckBkt,
                                                         base, hist1, hdr,
                                                         boxes6k, score6k, area6k, validW);
  sup_build_pre<<<dim3(2, PWRD, BB), 256, 0, stream>>>(boxes6k, area6k, validW, cnt, list);
  resolve_pre<<<BB, 1024, 0, stream>>>(cnt, list, validW, score6k, boxes6k, area6k, out);
}

// Round 20
// 91.196 us; speedup vs baseline: 1.8049x; 1.0141x over previous
//
#include <hip/hip_runtime.h>
#include <hip/hip_bf16.h>
#include <math.h>

typedef unsigned int uint;
typedef unsigned short ushort;
typedef unsigned long long u64;

#define BB 4
#define NN 100000
#define PRE 6000
#define POST 1000
#define NWRD 94          // 6000/64 rounded up
#define PREF 2048        // NMS prefix (exact if >=1000 kept inside; else in-block fallback)
#define PWRD 32          // PREF/64
#define SCAP 8192        // bucketed capacity
#define ROWP 6016        // padded rows/cols
#define KSUP 64          // max suppressors tracked per box
#define NRANGE 16        // hist ranges per image (4096 bins each)

// ---- workspace layout (bytes) ----
constexpr size_t OFF_HDR   = 0;                                    // uints: t1[4], limit[4]
constexpr size_t OFF_RTOT  = 64;                                   // 64 uints: per-(b,range) totals
constexpr size_t OFF_CNT   = 1024;                                 // BB*ROWP*4 (zeroed by hist_range)
constexpr size_t OFF_H1    = OFF_CNT + (size_t)BB*ROWP*4;          // hist1: 1MB (fully overwritten)
constexpr size_t OFF_BASE  = OFF_H1  + (size_t)BB*65536*4;         // base:  1MB (fully overwritten)
constexpr size_t OFF_BKT   = OFF_BASE+ (size_t)BB*65536*4;         // bkts:  BB*NN*2 (ushort)
constexpr size_t OFF_BUCK  = OFF_BKT + (size_t)BB*NN*2;            // keys:  BB*SCAP*8
constexpr size_t OFF_BBOX  = OFF_BUCK+ (size_t)BB*SCAP*8;          // boxes: BB*SCAP*16
constexpr size_t OFF_BSC   = OFF_BBOX+ (size_t)BB*SCAP*16;         // score: BB*SCAP*4
constexpr size_t OFF_BBKT  = OFF_BSC + (size_t)BB*SCAP*4;          // bkt:   BB*SCAP*2
constexpr size_t OFF_LIST  = OFF_BBKT+ (size_t)BB*SCAP*2;          // BB*ROWP*KSUP*4
constexpr size_t OFF_BOX   = OFF_LIST+ (size_t)BB*ROWP*KSUP*4;
constexpr size_t OFF_SCO   = OFF_BOX + (size_t)BB*ROWP*16;
constexpr size_t OFF_AREA  = OFF_SCO + (size_t)BB*ROWP*4;
constexpr size_t OFF_VAL   = OFF_AREA+ (size_t)BB*ROWP*4;          // validW (zeroed by scan128)

__device__ __forceinline__ float clipf(float v, float hi) {
  return fminf(fmaxf(v, 0.0f), hi);
}

// Uniform, weakly key-monotone bucket map (exactness: within-bucket ranking is
// by the exact (key,idx) compare, so any weakly monotone coarsening is exact).
__device__ __forceinline__ uint bucket_of(float s, bool valid) {
  if (!valid) return 65535u;
  float t = fminf(fmaxf(s, 0.0f), 1.0f);
  uint q = (uint)(t * 65536.0f);
  q = q > 65535u ? 65535u : q;
  return 65535u - q;                    // higher score -> lower bucket
}

// ---------- pass 1a: buckets only (pure streaming, no atomics) ----------
__global__ void bkts_only(const float4* __restrict__ props,
                          const float2* __restrict__ clsp,
                          ushort* __restrict__ bkts) {
  int b = blockIdx.y;
  int i = blockIdx.x * 256 + threadIdx.x;
  if (i >= NN) return;
  float4 p = props[(size_t)b * NN + i];
  float x1 = clipf(p.x, 800.0f), y1 = clipf(p.y, 800.0f);
  float x2 = clipf(p.z, 800.0f), y2 = clipf(p.w, 800.0f);
  bool valid = ((x2 - x1) >= 16.0f) && ((y2 - y1) >= 16.0f);
  float s  = clsp[(size_t)b * NN + i].y;
  bkts[(size_t)b * NN + i] = (ushort)bucket_of(s, valid);
}

// ---------- pass 1b: range-partitioned LDS histogram over bkts ----------
__global__ __launch_bounds__(256) void hist_range(const uint4* __restrict__ bkts4,
                                                  uint* __restrict__ hist1,
                                                  uint* __restrict__ rtot,
                                                  uint* __restrict__ cnt) {
  int b = blockIdx.y;
  int r = blockIdx.x;
  uint lo = (uint)r << 12;     // 4096 bins per range block
  __shared__ uint lh[4096];
  __shared__ uint wr[4];
  int tid = threadIdx.x, lane = tid & 63, W = tid >> 6;
  for (int i = tid; i < 4096; i += 256) lh[i] = 0u;
  __syncthreads();
  const uint4* K = bkts4 + (size_t)b * (NN / 8);   // 8 ushorts per uint4
  uint inv = 0;
  for (int i = tid; i < NN / 8; i += 256) {
    uint4 v = K[i];
    uint q;
    q = v.x & 0xFFFFu;  { uint d = q - lo; if (d < 4096u) { if (q == 0xFFFFu) inv++; else atomicAdd(&lh[d], 1u); } }
    q = v.x >> 16;      { uint d = q - lo; if (d < 4096u) { if (q == 0xFFFFu) inv++; else atomicAdd(&lh[d], 1u); } }
    q = v.y & 0xFFFFu;  { uint d = q - lo; if (d < 4096u) { if (q == 0xFFFFu) inv++; else atomicAdd(&lh[d], 1u); } }
    q = v.y >> 16;      { uint d = q - lo; if (d < 4096u) { if (q == 0xFFFFu) inv++; else atomicAdd(&lh[d], 1u); } }
    q = v.z & 0xFFFFu;  { uint d = q - lo; if (d < 4096u) { if (q == 0xFFFFu) inv++; else atomicAdd(&lh[d], 1u); } }
    q = v.z >> 16;      { uint d = q - lo; if (d < 4096u) { if (q == 0xFFFFu) inv++; else atomicAdd(&lh[d], 1u); } }
    q = v.w & 0xFFFFu;  { uint d = q - lo; if (d < 4096u) { if (q == 0xFFFFu) inv++; else atomicAdd(&lh[d], 1u); } }
    q = v.w >> 16;      { uint d = q - lo; if (d < 4096u) { if (q == 0xFFFFu) inv++; else atomicAdd(&lh[d], 1u); } }
  }
  if (inv) atomicAdd(&lh[4095], inv);   // only block r=15 ever has inv>0
  __syncthreads();
  uint* H = hist1 + (size_t)b * 65536 + lo;
  uint s = 0;
  for (int i = tid; i < 4096; i += 256) { H[i] = lh[i]; s += lh[i]; }
  for (int off = 32; off > 0; off >>= 1) s += __shfl_xor(s, off);
  if (lane == 0) wr[W] = s;
  __syncthreads();
  if (tid == 0) rtot[b * NRANGE + r] = wr[0] + wr[1] + wr[2] + wr[3];
  uint* C = cnt + (size_t)b * ROWP + r * (ROWP / NRANGE);
  for (int t = tid; t < ROWP / NRANGE; t += 256) C[t] = 0u;
}

// ---------- pass 2: per-range exclusive scan -> base[]; boundary -> hdr ----------
__global__ __launch_bounds__(256) void scan128(const uint* __restrict__ hist1,
                                               const uint* __restrict__ rtot,
                                               uint* __restrict__ base,
                                               uint* __restrict__ hdr,
                                               u64* __restrict__ validW) {
  int r = blockIdx.x, b = blockIdx.y;
  int tid = threadIdx.x, lane = tid & 63, W = tid >> 6;
  __shared__ uint wt[4];
  if (r == 0 && tid < 96) validW[(size_t)b * 96 + tid] = 0ull;
  uint lo = (uint)r << 12;
  uint rbase = 0, tot = 0;
  #pragma unroll
  for (int k = 0; k < NRANGE; ++k) {
    uint v = rtot[b * NRANGE + k];
    if (k < r) rbase += v;
    if (k == r) tot = v;
  }
  const uint* h = hist1 + (size_t)b * 65536 + lo;
  uint c[16], s = 0;
  #pragma unroll
  for (int k = 0; k < 16; ++k) { c[k] = h[tid * 16 + k]; s += c[k]; }
  uint ps = s;
  #pragma unroll
  for (int off = 1; off < 64; off <<= 1) {
    uint v = __shfl_up(ps, off);
    if (lane >= off) ps += v;
  }
  if (lane == 63) wt[W] = ps;
  __syncthreads();
  uint wbase = 0;
  #pragma unroll
  for (int k = 0; k < 4; ++k) { if (k < W) wbase += wt[k]; }
  uint excl = rbase + wbase + ps - s;     // global exclusive before thread's bins
  uint run = excl;
  uint* bs = base + (size_t)b * 65536 + lo;
  #pragma unroll
  for (int k = 0; k < 16; ++k) { bs[tid * 16 + k] = run; run += c[k]; }
  if (rbase < (uint)PRE && (uint)PRE <= rbase + tot) {
    uint cc = excl;
    #pragma unroll
    for (int k = 0; k < 16; ++k) {
      uint hv = c[k];
      if (cc < (uint)PRE && (uint)PRE <= cc + hv) {
        hdr[0 + b] = lo + (uint)(tid * 16 + k);  // t1 boundary bucket
        hdr[4 + b] = cc + hv;                    // limit = cumulative through t1
      }
      cc += hv;
    }
  }
}

// ---------- pass 3: scatter full records (key recomputed inline) ----------
__global__ void bucket_scatter(const ushort* __restrict__ bkts,
                               uint* __restrict__ base,
                               const uint* __restrict__ hdr,
                               const float4* __restrict__ props,
                               const float2* __restrict__ clsp,
                               u64* __restrict__ buck,
                               float4* __restrict__ buckBox,
                               float* __restrict__ buckSc,
                               ushort* __restrict__ buckBkt) {
  int b = blockIdx.y;
  int i = blockIdx.x * 256 + threadIdx.x;
  if (i >= NN) return;
  uint bk = bkts[(size_t)b * NN + i];
  if (bk <= hdr[0 + b]) {
    uint pos = atomicAdd(&base[(size_t)b * 65536 + bk], 1u);
    if (pos < SCAP) {
      float4 p = props[(size_t)b * NN + i];
      float4 bx;
      bx.x = clipf(p.x, 800.0f); bx.y = clipf(p.y, 800.0f);
      bx.z = clipf(p.z, 800.0f); bx.w = clipf(p.w, 800.0f);
      bool valid = ((bx.z - bx.x) >= 16.0f) && ((bx.w - bx.y) >= 16.0f);
      float s = clsp[(size_t)b * NN + i].y;
      float sm = valid ? s : -INFINITY;
      uint u = __float_as_uint(sm);
      u = (u & 0x80000000u) ? ~u : (u | 0x80000000u);  // monotonic map
      uint kh = ~u;                                     // ascending == DESC score
      buck[(size_t)b * SCAP + pos] = ((u64)kh << 32) | (uint)i;
      buckBox[(size_t)b * SCAP + pos] = bx;
      buckSc [(size_t)b * SCAP + pos] = s;
      buckBkt[(size_t)b * SCAP + pos] = (ushort)bk;
    }
  }
}

// ---------- pass 4: exact rank -> copy record from slot to rank row ----------
__global__ void rank_scatter(const u64* __restrict__ buck,
                             const float4* __restrict__ buckBox,
                             const float* __restrict__ buckSc,
                             const ushort* __restrict__ buckBkt,
                             const uint* __restrict__ base,
                             const uint* __restrict__ hist,
                             const uint* __restrict__ hdr,
                             float4* __restrict__ boxes6k,
                             float* __restrict__ score6k,
                             float* __restrict__ area6k,
                             u64* __restrict__ validW) {
  int b = blockIdx.y;
  int s = blockIdx.x * 256 + threadIdx.x;
  uint limit = hdr[4 + b];
  if (s >= (int)limit) return;
  u64 v = buck[(size_t)b * SCAP + s];
  float4 bx = buckBox[(size_t)b * SCAP + s];
  float sc = buckSc[(size_t)b * SCAP + s];
  uint bkt = buckBkt[(size_t)b * SCAP + s];
  uint cntb = hist[(size_t)b * 65536 + bkt];
  uint b0 = base[(size_t)b * 65536 + bkt] - cntb;  // restore pre-scatter base
  uint r = b0;
  for (uint m = 0; m < cntb; ++m) {
    u64 w = buck[(size_t)b * SCAP + b0 + m];
    r += (w < v) ? 1u : 0u;                        // (key,idx) stable order
  }
  if (r >= (uint)PRE) return;
  float w = bx.z - bx.x, h = bx.w - bx.y;
  bool valid = (w >= 16.0f) && (h >= 16.0f);
  boxes6k[(size_t)b * ROWP + r] = bx;
  score6k[(size_t)b * ROWP + r] = sc;
  area6k [(size_t)b * ROWP + r] = fmaxf(w, 0.0f) * fmaxf(h, 0.0f);
  if (valid) atomicOr(&validW[(size_t)b * 96 + (r >> 6)], 1ull << (r & 63));
}

// ---------- pass 5: prefix suppressor lists, fine-grained 64x64 tiles ----------
// Per-wave tile (gb rows x cb cols), cb >= gb only. Exact division-free IoU:
// fl32(inter/un) > 0.7f <=> (double)inter >= M*(double)un,
// M = 0.7f + 2^-25 = 0x1.6666668p-1 (rounding midpoint; tie rounds-to-even UP;
// 25b x 24b = 49 bits <= 53, conversions exact, un > 0).
__global__ __launch_bounds__(256) void sup_build_pre(const float4* __restrict__ boxes6k,
                                                     const float* __restrict__ area6k,
                                                     const u64* __restrict__ validW,
                                                     uint* __restrict__ cnt,
                                                     uint* __restrict__ list) {
  int gb = blockIdx.y, b = blockIdx.z;
  int sub = threadIdx.x >> 6, t = threadIdx.x & 63;
  int cb = blockIdx.x * 4 + sub;
  __shared__ float4 rbox[64];
  __shared__ float  rar[64];
  if (threadIdx.x < 64) {
    rbox[t] = boxes6k[(size_t)b * ROWP + gb * 64 + t];
    rar[t]  = area6k [(size_t)b * ROWP + gb * 64 + t];
  }
  __syncthreads();
  if (cb >= PWRD || cb < gb) return;
  u64 vmask = validW[(size_t)b * 96 + gb];
  u64 rowsel = (cb == gb) ? (t ? (vmask & ((1ull << t) - 1ull)) : 0ull) : vmask;
  int col = cb * 64 + t;
  float4 c = boxes6k[(size_t)b * ROWP + col];
  float ca = area6k[(size_t)b * ROWP + col];
  const double M = 0x1.6666668p-1;
  u64 bits = 0;
  #pragma unroll 4
  for (int r = 0; r < 64; ++r) {
    float4 rb = rbox[r];
    float xx1 = fmaxf(rb.x, c.x), yy1 = fmaxf(rb.y, c.y);
    float xx2 = fminf(rb.z, c.z), yy2 = fminf(rb.w, c.w);
    float inter = fmaxf(xx2 - xx1, 0.0f) * fmaxf(yy2 - yy1, 0.0f);
    float un = fmaxf(rar[r] + ca - inter, 1e-9f);
    bits |= ((double)inter >= M * (double)un) ? (1ull << r) : 0ull;
  }
  bits &= rowsel;
  int rbase = gb * 64;
  while (bits) {
    int r = __ffsll((long long)bits) - 1;
    bits &= bits - 1;
    uint pos = atomicAdd(&cnt[(size_t)b * ROWP + col], 1u);
    if (pos < KSUP) list[((size_t)b * ROWP + col) * KSUP + pos] = (uint)(rbase + r);
  }
}

// ---------- pass 6: prefix resolve + finalize, with exact in-block fallback ----
__global__ __launch_bounds__(1024) void resolve_pre(uint* __restrict__ cnt,
                                                    uint* __restrict__ list,
                                                    const u64* __restrict__ validW,
                                                    const float* __restrict__ score6k,
                                                    const float4* __restrict__ boxes6k,
                                                    const float* __restrict__ area6k,
                                                    float* __restrict__ out) {
  int b = blockIdx.x, tid = threadIdx.x, lane = tid & 63, wv = tid >> 6;
  __shared__ u64 ALIVE[96], DEC[96], VW[96];
  __shared__ int changed;
  __shared__ uint psum[NWRD + 1];
  __shared__ float4 rbox[64];
  __shared__ float  rar[64];
  if (tid < 96) {
    ALIVE[tid] = 0ull; DEC[tid] = 0ull;
    VW[tid] = validW[(size_t)b * 96 + tid];
  }
  __syncthreads();

  // ===== prefix resolve =====
  uint myCnt[2];
  #pragma unroll
  for (int r = 0; r < 2; ++r) {
    int j = tid + r * 1024;
    myCnt[r] = (j < PREF) ? cnt[(size_t)b * ROWP + j] : 0u;
  }
  #pragma unroll
  for (int r = 0; r < 2; ++r) {
    int j = tid + r * 1024;
    if (j >= PREF) continue;
    bool valid = (VW[j >> 6] >> (j & 63)) & 1ull;
    if (myCnt[r] == 0u || !valid) {
      atomicOr(&DEC[j >> 6], 1ull << (j & 63));
      if (valid) atomicOr(&ALIVE[j >> 6], 1ull << (j & 63));
    }
  }
  __syncthreads();
  while (true) {
    if (tid == 0) changed = 0;
    __syncthreads();
    int decJ[2]; bool decAlive[2];
    #pragma unroll
    for (int r = 0; r < 2; ++r) {
      decJ[r] = -1; decAlive[r] = false;
      int j = tid + r * 1024;
      if (j >= PREF || myCnt[r] == 0u) continue;
      if ((DEC[j >> 6] >> (j & 63)) & 1ull) continue;
      const uint* lj = list + ((size_t)b * ROWP + j) * KSUP;
      uint c = myCnt[r] < KSUP ? myCnt[r] : KSUP;
      bool anyAlive = false, pending = false;
      for (uint m = 0; m < c; ++m) {
        uint i = lj[m];
        bool ai = (ALIVE[i >> 6] >> (i & 63)) & 1ull;
        bool di = (DEC[i >> 6] >> (i & 63)) & 1ull;
        if (ai) { anyAlive = true; break; }
        if (!di) pending = true;
      }
      if (anyAlive)      { decJ[r] = j; decAlive[r] = false; }
      else if (!pending) { decJ[r] = j; decAlive[r] = true;  }
    }
    __syncthreads();
    bool any = false;
    #pragma unroll
    for (int r = 0; r < 2; ++r) {
      if (decJ[r] >= 0) {
        int j = decJ[r];
        if (decAlive[r]) atomicOr(&ALIVE[j >> 6], 1ull << (j & 63));
        atomicOr(&DEC[j >> 6], 1ull << (j & 63));
        any = true;
      }
    }
    if (any) atomicAdd(&changed, 1);
    __syncthreads();
    if (changed == 0) break;
  }

  if (tid == 0) {
    uint c = 0;
    for (int w = 0; w < PWRD; ++w) { psum[w] = c; c += (uint)__popcll(ALIVE[w]); }
    psum[PWRD] = c;
  }
  __syncthreads();

  if (psum[PWRD] >= (uint)POST) {
    // ===== fast path: finalize from prefix =====
    for (int q = tid; q < POST; q += 1024) out[(size_t)b * POST + q] = 0.0f;
    for (int t = tid; t < POST * 4; t += 1024) out[(size_t)BB * POST + (size_t)b * POST * 4 + t] = 0.0f;
    __syncthreads();
    for (int j = tid; j < PREF; j += 1024) {
      int w = j >> 6, bit = j & 63;
      u64 word = ALIVE[w];
      if ((word >> bit) & 1ull) {
        uint rank = psum[w] + (uint)__popcll(word & ((1ull << bit) - 1ull));
        if (rank < POST) {
          out[(size_t)b * POST + rank] = score6k[(size_t)b * ROWP + j];
          float4 bx = boxes6k[(size_t)b * ROWP + j];
          float* o = out + (size_t)BB * POST + ((size_t)b * POST + rank) * 4;
          o[0] = bx.x; o[1] = bx.y; o[2] = bx.z; o[3] = bx.w;
        }
      }
    }
    return;
  }

  // ===== exact fallback (never taken on this data) =====
  const double M = 0x1.6666668p-1;
  for (int gb = 0; gb < NWRD; ++gb) {
    __syncthreads();
    if (tid < 64) {
      rbox[tid] = boxes6k[(size_t)b * ROWP + gb * 64 + tid];
      rar[tid]  = area6k [(size_t)b * ROWP + gb * 64 + tid];
    }
    __syncthreads();
    u64 vmask = VW[gb];
    for (int cw = gb + wv; cw < NWRD; cw += 16) {
      if (gb < PWRD && cw < PWRD) continue;   // prefix pairs already built
      int col = cw * 64 + lane;
      int colc = col < (ROWP - 1) ? col : (ROWP - 1);
      float4 c = boxes6k[(size_t)b * ROWP + colc];
      float ca = area6k[(size_t)b * ROWP + colc];
      u64 rowsel = (cw > gb) ? vmask
                 : (lane ? (vmask & ((1ull << lane) - 1ull)) : 0ull);
      u64 bits = 0;
      #pragma unroll 4
      for (int r = 0; r < 64; ++r) {
        float4 rb = rbox[r];
        float xx1 = fmaxf(rb.x, c.x), yy1 = fmaxf(rb.y, c.y);
        float xx2 = fminf(rb.z, c.z), yy2 = fminf(rb.w, c.w);
        float inter = fmaxf(xx2 - xx1, 0.0f) * fmaxf(yy2 - yy1, 0.0f);
        float un = fmaxf(rar[r] + ca - inter, 1e-9f);
        bits |= ((double)inter >= M * (double)un) ? (1ull << r) : 0ull;
      }
      bits &= rowsel;
      while (bits) {
        int r = __ffsll((long long)bits) - 1;
        bits &= bits - 1;
        uint pos = atomicAdd(&cnt[(size_t)b * ROWP + col], 1u);
        if (pos < KSUP) list[((size_t)b * ROWP + col) * KSUP + pos] = (uint)(gb * 64 + r);
      }
    }
  }
  __syncthreads();

  if (tid < 96) { ALIVE[tid] = 0ull; DEC[tid] = 0ull; }
  __syncthreads();
  uint myCnt6[6];
  #pragma unroll
  for (int r = 0; r < 6; ++r) {
    int j = tid + r * 1024;
    myCnt6[r] = (j < PRE) ? cnt[(size_t)b * ROWP + j] : 0u;
  }
  #pragma unroll
  for (int r = 0; r < 6; ++r) {
    int j = tid + r * 1024;
    if (j >= PRE) continue;
    bool valid = (VW[j >> 6] >> (j & 63)) & 1ull;
    if (myCnt6[r] == 0u || !valid) {
      atomicOr(&DEC[j >> 6], 1ull << (j & 63));
      if (valid) atomicOr(&ALIVE[j >> 6], 1ull << (j & 63));
    }
  }
  __syncthreads();
  while (true) {
    if (tid == 0) changed = 0;
    __syncthreads();
    int decJ[6]; bool decAlive[6];
    #pragma unroll
    for (int r = 0; r < 6; ++r) {
      decJ[r] = -1; decAlive[r] = false;
      int j = tid + r * 1024;
      if (j >= PRE || myCnt6[r] == 0u) continue;
      if ((DEC[j >> 6] >> (j & 63)) & 1ull) continue;
      const uint* lj = list + ((size_t)b * ROWP + j) * KSUP;
      uint c = myCnt6[r] < KSUP ? myCnt6[r] : KSUP;
      bool anyAlive = false, pending = false;
      for (uint m = 0; m < c; ++m) {
        uint i = lj[m];
        bool ai = (ALIVE[i >> 6] >> (i & 63)) & 1ull;
        bool di = (DEC[i >> 6] >> (i & 63)) & 1ull;
        if (ai) { anyAlive = true; break; }
        if (!di) pending = true;
      }
      if (anyAlive)      { decJ[r] = j; decAlive[r] = false; }
      else if (!pending) { decJ[r] = j; decAlive[r] = true;  }
    }
    __syncthreads();
    bool any = false;
    #pragma unroll
    for (int r = 0; r < 6; ++r) {
      if (decJ[r] >= 0) {
        int j = decJ[r];
        if (decAlive[r]) atomicOr(&ALIVE[j >> 6], 1ull << (j & 63));
        atomicOr(&DEC[j >> 6], 1ull << (j & 63));
        any = true;
      }
    }
    if (any) atomicAdd(&changed, 1);
    __syncthreads();
    if (changed == 0) break;
  }

  if (tid == 0) {
    uint c = 0;
    for (int w = 0; w < NWRD; ++w) { psum[w] = c; c += (uint)__popcll(ALIVE[w]); }
    psum[NWRD] = c;
  }
  __syncthreads();
  for (int q = tid; q < POST; q += 1024) out[(size_t)b * POST + q] = 0.0f;
  for (int t = tid; t < POST * 4; t += 1024) out[(size_t)BB * POST + (size_t)b * POST * 4 + t] = 0.0f;
  __syncthreads();
  for (int j = tid; j < PRE; j += 1024) {
    int w = j >> 6, bit = j & 63;
    u64 word = ALIVE[w];
    if ((word >> bit) & 1ull) {
      uint rank = psum[w] + (uint)__popcll(word & ((1ull << bit) - 1ull));
      if (rank < POST) {
        out[(size_t)b * POST + rank] = score6k[(size_t)b * ROWP + j];
        float4 bx = boxes6k[(size_t)b * ROWP + j];
        float* o = out + (size_t)BB * POST + ((size_t)b * POST + rank) * 4;
        o[0] = bx.x; o[1] = bx.y; o[2] = bx.z; o[3] = bx.w;
      }
    }
  }
}

extern "C" void kernel_launch(void* const* d_in, const int* in_sizes, int n_in,
                              void* d_out, int out_size, void* d_ws, size_t ws_size,
                              hipStream_t stream) {
  const float4* props = (const float4*)d_in[0];
  const float2* clsp  = (const float2*)d_in[1];
  float* out = (float*)d_out;
  char* ws = (char*)d_ws;

  uint*   hdr     = (uint*)(ws + OFF_HDR);
  uint*   rtot    = (uint*)(ws + OFF_RTOT);
  uint*   cnt     = (uint*)(ws + OFF_CNT);
  uint*   hist1   = (uint*)(ws + OFF_H1);
  uint*   base    = (uint*)(ws + OFF_BASE);
  ushort* bkts    = (ushort*)(ws + OFF_BKT);
  u64*    buck    = (u64*) (ws + OFF_BUCK);
  float4* buckBox = (float4*)(ws + OFF_BBOX);
  float*  buckSc  = (float*)(ws + OFF_BSC);
  ushort* buckBkt = (ushort*)(ws + OFF_BBKT);
  uint*   list    = (uint*)(ws + OFF_LIST);
  float4* boxes6k = (float4*)(ws + OFF_BOX);
  float*  score6k = (float*)(ws + OFF_SCO);
  float*  area6k  = (float*)(ws + OFF_AREA);
  u64*    validW  = (u64*) (ws + OFF_VAL);

  dim3 gN((NN + 255) / 256, BB);
  bkts_only<<<gN, 256, 0, stream>>>(props, clsp, bkts);
  hist_range<<<dim3(NRANGE, BB), 256, 0, stream>>>((const uint4*)bkts, hist1, rtot, cnt);
  scan128<<<dim3(NRANGE, BB), 256, 0, stream>>>(hist1, rtot, base, hdr, validW);
  bucket_scatter<<<gN, 256, 0, stream>>>(bkts, base, hdr, props, clsp,
                                         buck, buckBox, buckSc, buckBkt);
  rank_scatter<<<dim3(SCAP / 256, BB), 256, 0, stream>>>(buck, buckBox, buckSc, buckBkt,
                                                         base, hist1, hdr,
                                                         boxes6k, score6k, area6k, validW);
  sup_build_pre<<<dim3(PWRD / 4, PWRD, BB), 256, 0, stream>>>(boxes6k, area6k, validW, cnt, list);
  resolve_pre<<<BB, 1024, 0, stream>>>(cnt, list, validW, score6k, boxes6k, area6k, out);
}